// Round 1
// baseline (3950.044 us; speedup 1.0000x reference)
//
#include <hip/hip_runtime.h>

#define BIT 64
#define NCLASS 100
#define NTRAIN 100000
#define BATCH 512
// config scalars: MU=1, M=1, ETA=0.5, VUL=1, NTA=1

// ---- workspace element offsets (4-byte slots), total ~960 KB ----
#define O_OWNER   0                          // int[100000]
#define O_TLAB    100000                     // int[100000]
#define O_LAB     200000                     // int[512]
#define O_BMAT    200512                     // float[64*512]
#define O_BSUM    233280                     // float[64*100]
#define O_COUNT   239680                     // float[100]
#define O_QSUM    239780                     // double (8B aligned)
#define O_MSUM    239782                     // double

__device__ __forceinline__ float signf(float x) {
    return (x > 0.f) ? 1.f : ((x < 0.f) ? -1.f : 0.f);
}

// labels of the batch + scatter owner map (last-write-wins == max batch idx)
__global__ void k_prep(const float* __restrict__ y, const int* __restrict__ ind,
                       int* owner, int* lab) {
    int b = threadIdx.x;  // 512 threads, 1 block
    const float* row = y + b * NCLASS;
    int best = 0;
    for (int c = 0; c < NCLASS; ++c)
        if (row[c] > 0.5f) best = c;
    lab[b] = best;
    atomicMax(&owner[ind[b]], b);
}

// train labels from one-hot Y, patched by the scatter
__global__ void k_tlab(const float* __restrict__ Y, const int* __restrict__ owner,
                       const int* __restrict__ lab, int* tlab) {
    int j = blockIdx.x * blockDim.x + threadIdx.x;
    if (j >= NTRAIN) return;
    int tl = 0;
    for (int c = 0; c < NCLASS; ++c)
        if (Y[(size_t)c * NTRAIN + j] > 0.5f) tl = c;
    int ow = owner[j];
    tlab[j] = (ow >= 0) ? lab[ow] : tl;
}

// b = sign(MU*sign(V)[:,lab] + u^T)  [64,512], plus quantization-loss sum
__global__ void k_b(const float* __restrict__ u, const float* __restrict__ V,
                    const int* __restrict__ lab, float* bmat, double* qsum) {
    int bb = threadIdx.x;   // 512
    int r  = blockIdx.x;    // 64
    int c = lab[bb];
    float v  = V[r * NCLASS + c];
    float uu = u[bb * BIT + r];
    float t  = signf(v) + uu;            // MU = 1
    float bv = signf(t);
    bmat[r * BATCH + bb] = bv;
    float d = bv - uu;
    double q = (double)(d * d);
    for (int off = 32; off; off >>= 1) q += __shfl_down(q, off);
    __shared__ double wsum[8];
    int wid = threadIdx.x >> 6, lane = threadIdx.x & 63;
    if (lane == 0) wsum[wid] = q;
    __syncthreads();
    if (threadIdx.x == 0) {
        double s = 0;
        for (int w = 0; w < 8; ++w) s += wsum[w];
        atomicAdd(qsum, s);
    }
}

// deterministic per-class accumulation: Bsum[r,c] = sum_{b: lab[b]=c} bmat[r,b]
__global__ void k_bsum(const float* __restrict__ bmat, const int* __restrict__ lab,
                       float* Bsum, float* count) {
    __shared__ int slab[BATCH];
    for (int i = threadIdx.x; i < BATCH; i += blockDim.x) slab[i] = lab[i];
    __syncthreads();
    int idx = blockIdx.x * blockDim.x + threadIdx.x;  // 6400
    if (idx < BIT * NCLASS) {
        int r = idx / NCLASS, c = idx % NCLASS;
        const float* br = bmat + r * BATCH;
        float s = 0.f;
        for (int bb = 0; bb < BATCH; ++bb)
            if (slab[bb] == c) s += br[bb];
        Bsum[idx] = s;
    }
    if (blockIdx.x == 0 && threadIdx.x < NCLASS) {
        int c = threadIdx.x, n = 0;
        for (int bb = 0; bb < BATCH; ++bb)
            if (slab[bb] == c) ++n;
        count[c] = (float)n;
    }
}

// 200-step GD on V. Single block, LDS-resident Vc.
// grad = ci*(count[c]*V - Bsum) + ce*((VV^T)V - 64*(2V - rowsum)) + cq*(V - sign(V))
__global__ __launch_bounds__(1024) void k_gd(const float* __restrict__ V,
                                             const float* __restrict__ Bsum,
                                             const float* __restrict__ count,
                                             float* out) {
    __shared__ float Vc[BIT * NCLASS];
    __shared__ float Mm[BIT * BIT];
    __shared__ float rs[BIT];
    int t = threadIdx.x;
    for (int i = t; i < BIT * NCLASS; i += 1024) Vc[i] = V[i];

    // upper-triangle 4x4-tile mapping for symmetric M (136 tiles of 16x16 grid)
    int ti = 0, tj = 0;
    bool mact = (t < 136);
    if (mact) {
        int rem = t, a = 0;
        while (rem >= 16 - a) { rem -= 16 - a; ++a; }
        ti = a; tj = a + rem;
    }
    bool pact = (t < 400);
    int pi0 = 0, pc0 = 0;
    if (pact) { pi0 = (t / 25) * 4; pc0 = (t % 25) * 4; }
    __syncthreads();

    const float ci = 2.0f / 32768.0f;   // intra: mean over 64*512
    const float ce = 4.0f / 10000.0f;   // inter (VUL=1): 4/100^2
    const float cq = 2.0f / 6400.0f;    // quant (NTA=1)

    for (int step = 0; step < 200; ++step) {
        float alpha = 0.03f;
        if (step >= 149) alpha *= 0.1f;
        if (step >= 179) alpha *= 0.1f;

        if (t < BIT) {               // row sums of current Vc
            float s = 0.f;
            for (int c = 0; c < NCLASS; ++c) s += Vc[t * NCLASS + c];
            rs[t] = s;
        }
        if (mact) {                  // M = Vc * Vc^T (64x64), symmetric
            int i0 = ti * 4, j0 = tj * 4;
            float m[4][4] = {};
            for (int c = 0; c < NCLASS; ++c) {
                float a[4], b2[4];
                #pragma unroll
                for (int x = 0; x < 4; ++x) a[x] = Vc[(i0 + x) * NCLASS + c];
                #pragma unroll
                for (int yv = 0; yv < 4; ++yv) b2[yv] = Vc[(j0 + yv) * NCLASS + c];
                #pragma unroll
                for (int x = 0; x < 4; ++x)
                    #pragma unroll
                    for (int yv = 0; yv < 4; ++yv) m[x][yv] += a[x] * b2[yv];
            }
            #pragma unroll
            for (int x = 0; x < 4; ++x)
                #pragma unroll
                for (int yv = 0; yv < 4; ++yv) {
                    Mm[(i0 + x) * BIT + (j0 + yv)] = m[x][yv];
                    Mm[(j0 + yv) * BIT + (i0 + x)] = m[x][yv];
                }
        }
        __syncthreads();

        float p[4][4] = {};
        if (pact) {                  // P = M @ Vc (64x100)
            for (int k = 0; k < BIT; ++k) {
                float a[4], b2[4];
                #pragma unroll
                for (int x = 0; x < 4; ++x) a[x] = Mm[(pi0 + x) * BIT + k];
                #pragma unroll
                for (int yv = 0; yv < 4; ++yv) b2[yv] = Vc[k * NCLASS + pc0 + yv];
                #pragma unroll
                for (int x = 0; x < 4; ++x)
                    #pragma unroll
                    for (int yv = 0; yv < 4; ++yv) p[x][yv] += a[x] * b2[yv];
            }
        }
        __syncthreads();             // all reads of old Vc done

        if (pact) {
            #pragma unroll
            for (int x = 0; x < 4; ++x)
                #pragma unroll
                for (int yv = 0; yv < 4; ++yv) {
                    int r = pi0 + x, c = pc0 + yv;
                    float v = Vc[r * NCLASS + c];
                    float g = ci * (count[c] * v - Bsum[r * NCLASS + c])
                            + ce * (p[x][yv] - 64.0f * (2.0f * v - rs[r]))
                            + cq * (v - signf(v));
                    Vc[r * NCLASS + c] = v - alpha * g;
                }
        }
        __syncthreads();
    }
    for (int i = t; i < BIT * NCLASS; i += 1024) out[1 + i] = Vc[i];
}

// fused ip = clip(0.5*u@U', -100, 50) + softplus + mean-reduce.
// Column j comes from u[owner[j],:] when scattered, else U[:,j].
__global__ __launch_bounds__(256) void k_metric(const float* __restrict__ u,
                                                const float* __restrict__ U,
                                                const int* __restrict__ lab,
                                                const int* __restrict__ tlab,
                                                const int* __restrict__ owner,
                                                double* msum) {
    int j = blockIdx.x * blockDim.x + threadIdx.x;
    float lsum = 0.f;
    if (j < NTRAIN) {
        int tl = tlab[j];
        int ow = owner[j];
        const float* colbase;
        size_t cstride;
        if (ow >= 0) { colbase = u + (size_t)ow * BIT; cstride = 1; }
        else         { colbase = U + j;                cstride = NTRAIN; }
        for (int b0 = 0; b0 < BATCH; b0 += 16) {
            float acc[16];
            #pragma unroll
            for (int k = 0; k < 16; ++k) acc[k] = 0.f;
            for (int r = 0; r < BIT; ++r) {
                float Uv = colbase[(size_t)r * cstride];
                #pragma unroll
                for (int k = 0; k < 16; ++k)
                    acc[k] += u[(b0 + k) * BIT + r] * Uv;   // uniform -> s_load
            }
            #pragma unroll
            for (int k = 0; k < 16; ++k) {
                float ip = 0.5f * acc[k];
                ip = fminf(fmaxf(ip, -100.f), 50.f);
                bool s = (lab[b0 + k] == tl);
                float x = s ? (1.0f - ip) : (1.0f + ip);   // M = 1
                lsum += fmaxf(x, 0.f) + log1pf(expf(-fabsf(x)));
            }
        }
    }
    double d = (double)lsum;
    for (int off = 32; off; off >>= 1) d += __shfl_down(d, off);
    __shared__ double wsum[4];
    int wid = threadIdx.x >> 6, lane = threadIdx.x & 63;
    if (lane == 0) wsum[wid] = d;
    __syncthreads();
    if (threadIdx.x == 0) {
        double s = 0;
        for (int w = 0; w < 4; ++w) s += wsum[w];
        atomicAdd(msum, s);
    }
}

__global__ void k_final(const double* __restrict__ msum,
                        const double* __restrict__ qsum, float* out) {
    if (threadIdx.x == 0) {
        double loss = (*msum) / ((double)BATCH * (double)NTRAIN)
                    + 0.5 * ((*qsum) / ((double)BIT * (double)BATCH));
        out[0] = (float)loss;
    }
}

extern "C" void kernel_launch(void* const* d_in, const int* in_sizes, int n_in,
                              void* d_out, int out_size, void* d_ws, size_t ws_size,
                              hipStream_t stream) {
    const float* u   = (const float*)d_in[0];
    const float* y   = (const float*)d_in[1];
    const int*   ind = (const int*)d_in[2];
    const float* U   = (const float*)d_in[3];
    const float* Y   = (const float*)d_in[4];
    const float* V   = (const float*)d_in[5];
    float* out = (float*)d_out;

    int*   wsI = (int*)d_ws;
    float* wsF = (float*)d_ws;
    int*   owner = wsI + O_OWNER;
    int*   tlab  = wsI + O_TLAB;
    int*   lab   = wsI + O_LAB;
    float* bmat  = wsF + O_BMAT;
    float* Bsum  = wsF + O_BSUM;
    float* count = wsF + O_COUNT;
    double* qsum = (double*)(wsF + O_QSUM);
    double* msum = (double*)(wsF + O_MSUM);

    hipMemsetAsync(owner, 0xFF, NTRAIN * sizeof(int), stream);        // -1
    hipMemsetAsync(wsF + O_QSUM, 0, 4 * sizeof(float), stream);       // qsum,msum

    k_prep<<<1, 512, 0, stream>>>(y, ind, owner, lab);
    k_tlab<<<(NTRAIN + 255) / 256, 256, 0, stream>>>(Y, owner, lab, tlab);
    k_b<<<64, 512, 0, stream>>>(u, V, lab, bmat, qsum);
    k_bsum<<<25, 256, 0, stream>>>(bmat, lab, Bsum, count);
    k_metric<<<(NTRAIN + 255) / 256, 256, 0, stream>>>(u, U, lab, tlab, owner, msum);
    k_gd<<<1, 1024, 0, stream>>>(V, Bsum, count, out);
    k_final<<<1, 64, 0, stream>>>(msum, qsum, out);
}

// Round 2
// 2678.131 us; speedup vs baseline: 1.4749x; 1.4749x over previous
//
#include <hip/hip_runtime.h>

#define BIT 64
#define NCLASS 100
#define NTRAIN 100000
#define BATCH 512
// config scalars: MU=1, M=1, ETA=0.5, VUL=1, NTA=1

// ---- workspace element offsets (4-byte slots) ----
#define O_OWNER   0                          // int[100000]
#define O_TLAB    100000                     // int[100000]
#define O_LAB     200000                     // int[512]
#define O_BMAT    200512                     // float[64*512]
#define O_BSUM    233280                     // float[64*100]
#define O_COUNT   239680                     // float[100]
#define O_QSUM    239780                     // double (8B aligned)
#define O_MSUM    239782                     // double

__device__ __forceinline__ float signf(float x) {
    return (x > 0.f) ? 1.f : ((x < 0.f) ? -1.f : 0.f);
}

// labels of the batch + scatter owner map (last-write-wins == max batch idx)
__global__ void k_prep(const float* __restrict__ y, const int* __restrict__ ind,
                       int* owner, int* lab) {
    int b = threadIdx.x;  // 512 threads, 1 block
    const float* row = y + b * NCLASS;
    int best = 0;
    for (int c = 0; c < NCLASS; ++c)
        if (row[c] > 0.5f) best = c;
    lab[b] = best;
    atomicMax(&owner[ind[b]], b);
}

// train labels from one-hot Y, patched by the scatter
__global__ void k_tlab(const float* __restrict__ Y, const int* __restrict__ owner,
                       const int* __restrict__ lab, int* tlab) {
    int j = blockIdx.x * blockDim.x + threadIdx.x;
    if (j >= NTRAIN) return;
    int tl = 0;
    for (int c = 0; c < NCLASS; ++c)
        if (Y[(size_t)c * NTRAIN + j] > 0.5f) tl = c;
    int ow = owner[j];
    tlab[j] = (ow >= 0) ? lab[ow] : tl;
}

// b = sign(MU*sign(V)[:,lab] + u^T)  [64,512], plus quantization-loss sum
__global__ void k_b(const float* __restrict__ u, const float* __restrict__ V,
                    const int* __restrict__ lab, float* bmat, double* qsum) {
    int bb = threadIdx.x;   // 512
    int r  = blockIdx.x;    // 64
    int c = lab[bb];
    float v  = V[r * NCLASS + c];
    float uu = u[bb * BIT + r];
    float t  = signf(v) + uu;            // MU = 1
    float bv = signf(t);
    bmat[r * BATCH + bb] = bv;
    float d = bv - uu;
    double q = (double)(d * d);
    for (int off = 32; off; off >>= 1) q += __shfl_down(q, off);
    __shared__ double wsum[8];
    int wid = threadIdx.x >> 6, lane = threadIdx.x & 63;
    if (lane == 0) wsum[wid] = q;
    __syncthreads();
    if (threadIdx.x == 0) {
        double s = 0;
        for (int w = 0; w < 8; ++w) s += wsum[w];
        atomicAdd(qsum, s);
    }
}

// deterministic per-class accumulation: Bsum[r,c] = sum_{b: lab[b]=c} bmat[r,b]
__global__ void k_bsum(const float* __restrict__ bmat, const int* __restrict__ lab,
                       float* Bsum, float* count) {
    __shared__ int slab[BATCH];
    for (int i = threadIdx.x; i < BATCH; i += blockDim.x) slab[i] = lab[i];
    __syncthreads();
    int idx = blockIdx.x * blockDim.x + threadIdx.x;  // 6400
    if (idx < BIT * NCLASS) {
        int r = idx / NCLASS, c = idx % NCLASS;
        const float* br = bmat + r * BATCH;
        float s = 0.f;
        for (int bb = 0; bb < BATCH; ++bb)
            if (slab[bb] == c) s += br[bb];
        Bsum[idx] = s;
    }
    if (blockIdx.x == 0 && threadIdx.x < NCLASS) {
        int c = threadIdx.x, n = 0;
        for (int bb = 0; bb < BATCH; ++bb)
            if (slab[bb] == c) ++n;
        count[c] = (float)n;
    }
}

// ---------------------------------------------------------------------------
// 200-step GD on V. Single block, 1024 threads, LDS-resident V (col-major).
//
// Layouts (all padded to kill bank conflicts):
//   Vb[c*66 + r] : V column-major, stride 66  (c=0..103, cols 100..103 = 0)
//   Mst[a*68 + b]: M = V V^T (symmetric), stride 68
//
// Phase M : all 1024 threads; 256 4x4 tiles x 4-way k-split on adjacent
//           lanes (kq = lane&3), reduced via __shfl_xor(1/2). a-rows are
//           wave-uniform (i0 = 4*wave) -> broadcast loads.
// Phase P : threads 0..831: 8 rows x 1 own column; threads 960..1023: rowsums.
// Update  : column-private -> race-free; 3 barriers/step total.
// ---------------------------------------------------------------------------
#define SVB 66
#define SM  68
__global__ __launch_bounds__(1024) void k_gd(const float* __restrict__ V,
                                             const float* __restrict__ Bsum,
                                             const float* __restrict__ count,
                                             float* __restrict__ out) {
    __shared__ float Vb[104 * SVB];
    __shared__ float Mst[64 * SM];
    __shared__ float rs[64];
    const int t = threadIdx.x;
    const int l = t & 63;
    const int w = t >> 6;        // wave 0..15

    for (int i = t; i < 104 * 64; i += 1024) {
        int c = i >> 6, r = i & 63;
        Vb[c * SVB + r] = (c < NCLASS) ? V[r * NCLASS + c] : 0.f;
    }

    // M-phase mapping
    const int kq = l & 3;          // k-quarter (adjacent lanes)
    const int tj = l >> 2;         // 0..15 col-tile
    const int i0 = 4 * w;          // row-tile (wave-uniform)
    const int j0 = 4 * tj;
    const int cbase = kq * 26;     // 4 x 26 = 104 columns (pads are zero)

    // P-phase mapping
    const bool pact = (t < 832);
    const int g8 = (t / 104) * 8;  // row-block base (0,8,...,56)
    const int pc = t % 104;        // own column
    const bool live = pact && (pc < NCLASS);

    float cnt = 0.f;
    float bs[8];
    #pragma unroll
    for (int x = 0; x < 8; ++x) bs[x] = 0.f;
    if (live) {
        cnt = count[pc];
        #pragma unroll
        for (int x = 0; x < 8; ++x) bs[x] = Bsum[(g8 + x) * NCLASS + pc];
    }

    const float ci = 2.0f / 32768.0f;   // intra: mean over 64*512
    const float ce = 4.0f / 10000.0f;   // inter (VUL=1): 4/100^2
    const float cq = 2.0f / 6400.0f;    // quant (NTA=1)

    __syncthreads();

    for (int step = 0; step < 200; ++step) {
        float alpha = 0.03f;
        if (step >= 149) alpha *= 0.1f;
        if (step >= 179) alpha *= 0.1f;

        // ---- M = V V^T (k-split over adjacent lanes) ----
        float m[4][4];
        #pragma unroll
        for (int x = 0; x < 4; ++x)
            #pragma unroll
            for (int yv = 0; yv < 4; ++yv) m[x][yv] = 0.f;

        for (int it = 0; it < 26; ++it) {
            const float* col = &Vb[(cbase + it) * SVB];
            float2 a01 = *(const float2*)&col[i0];
            float2 a23 = *(const float2*)&col[i0 + 2];
            float2 b01 = *(const float2*)&col[j0];
            float2 b23 = *(const float2*)&col[j0 + 2];
            float a[4] = {a01.x, a01.y, a23.x, a23.y};
            float b[4] = {b01.x, b01.y, b23.x, b23.y};
            #pragma unroll
            for (int x = 0; x < 4; ++x)
                #pragma unroll
                for (int yv = 0; yv < 4; ++yv) m[x][yv] += a[x] * b[yv];
        }
        #pragma unroll
        for (int x = 0; x < 4; ++x)
            #pragma unroll
            for (int yv = 0; yv < 4; ++yv) {
                m[x][yv] += __shfl_xor(m[x][yv], 1);
                m[x][yv] += __shfl_xor(m[x][yv], 2);
            }
        if (kq == 0) {
            #pragma unroll
            for (int x = 0; x < 4; ++x) {
                float4 v4 = make_float4(m[x][0], m[x][1], m[x][2], m[x][3]);
                *(float4*)&Mst[(i0 + x) * SM + j0] = v4;
            }
        }
        __syncthreads();

        // ---- P = M @ V (own column) ; rowsums on idle threads ----
        float p[8];
        #pragma unroll
        for (int x = 0; x < 8; ++x) p[x] = 0.f;
        if (pact) {
            const float* colp = &Vb[pc * SVB];
            #pragma unroll 4
            for (int k = 0; k < 64; k += 2) {
                float2 bv = *(const float2*)&colp[k];
                const float* mr0 = &Mst[k * SM + g8];
                const float* mr1 = &Mst[(k + 1) * SM + g8];
                float4 a0 = *(const float4*)&mr0[0];
                float4 a1 = *(const float4*)&mr0[4];
                float4 c0 = *(const float4*)&mr1[0];
                float4 c1 = *(const float4*)&mr1[4];
                p[0] += a0.x * bv.x; p[1] += a0.y * bv.x;
                p[2] += a0.z * bv.x; p[3] += a0.w * bv.x;
                p[4] += a1.x * bv.x; p[5] += a1.y * bv.x;
                p[6] += a1.z * bv.x; p[7] += a1.w * bv.x;
                p[0] += c0.x * bv.y; p[1] += c0.y * bv.y;
                p[2] += c0.z * bv.y; p[3] += c0.w * bv.y;
                p[4] += c1.x * bv.y; p[5] += c1.y * bv.y;
                p[6] += c1.z * bv.y; p[7] += c1.w * bv.y;
            }
        } else if (t >= 960) {
            int r = t - 960;
            float s = 0.f;
            for (int c = 0; c < NCLASS; ++c) s += Vb[c * SVB + r];
            rs[r] = s;
        }
        __syncthreads();

        // ---- update own column ----
        if (live) {
            #pragma unroll
            for (int x = 0; x < 8; ++x) {
                int r = g8 + x;
                float v = Vb[pc * SVB + r];
                float gg = ci * (cnt * v - bs[x])
                         + ce * (p[x] - 64.0f * (2.0f * v - rs[r]))
                         + cq * (v - signf(v));
                Vb[pc * SVB + r] = v - alpha * gg;
            }
        }
        __syncthreads();
    }

    if (live) {
        #pragma unroll
        for (int x = 0; x < 8; ++x)
            out[1 + (g8 + x) * NCLASS + pc] = Vb[pc * SVB + (g8 + x)];
    }
}

// ---------------------------------------------------------------------------
// Metric loss: ip = clip(0.5 * u @ Ueff, -100, 50); softplus; mean.
// Per thread: one train column j; 8 chunks of 64 batch rows; u^T staged in
// LDS (all-lane-broadcast float4 reads); 64 register accumulators.
// Column j comes from u[owner[j],:] when scattered, else U[:,j].
// ---------------------------------------------------------------------------
__global__ __launch_bounds__(256) void k_metric(const float* __restrict__ u,
                                                const float* __restrict__ U,
                                                const int* __restrict__ lab,
                                                const int* __restrict__ tlab,
                                                const int* __restrict__ owner,
                                                double* msum) {
    __shared__ float ut[64 * 68];   // u^T chunk: ut[r*68 + k]
    __shared__ int slab[BATCH];
    int j = blockIdx.x * blockDim.x + threadIdx.x;

    for (int i = threadIdx.x; i < BATCH; i += 256) slab[i] = lab[i];

    int tl = 0;
    const float* colbase = U;
    size_t cstride = NTRAIN;
    if (j < NTRAIN) {
        tl = tlab[j];
        int ow = owner[j];
        if (ow >= 0) { colbase = u + (size_t)ow * BIT; cstride = 1; }
        else         { colbase = U + j; }
    }

    float lsum = 0.f;
    for (int b0 = 0; b0 < BATCH; b0 += 64) {
        __syncthreads();   // previous chunk's readers done
        for (int i = threadIdx.x; i < 64 * 64; i += 256) {
            int k = i >> 6, r = i & 63;
            ut[r * 68 + k] = u[(b0 + k) * BIT + r];   // coalesced read
        }
        __syncthreads();

        if (j < NTRAIN) {
            float acc[64];
            #pragma unroll
            for (int k = 0; k < 64; ++k) acc[k] = 0.f;
            for (int r = 0; r < BIT; ++r) {
                float Uv = colbase[(size_t)r * cstride];
                const float* urow = &ut[r * 68];
                #pragma unroll
                for (int q = 0; q < 16; ++q) {
                    float4 uv = *(const float4*)&urow[q * 4];
                    acc[4 * q + 0] += uv.x * Uv;
                    acc[4 * q + 1] += uv.y * Uv;
                    acc[4 * q + 2] += uv.z * Uv;
                    acc[4 * q + 3] += uv.w * Uv;
                }
            }
            #pragma unroll
            for (int k = 0; k < 64; ++k) {
                float ip = fminf(fmaxf(0.5f * acc[k], -100.f), 50.f);
                float x = (slab[b0 + k] == tl) ? (1.0f - ip) : (1.0f + ip); // M=1
                lsum += fmaxf(x, 0.f) + __logf(1.f + __expf(-fabsf(x)));
            }
        }
    }

    double d = (double)lsum;
    for (int off = 32; off; off >>= 1) d += __shfl_down(d, off);
    __shared__ double wsum[4];
    int wid = threadIdx.x >> 6, lane = threadIdx.x & 63;
    if (lane == 0) wsum[wid] = d;
    __syncthreads();
    if (threadIdx.x == 0) {
        double s = 0;
        for (int w = 0; w < 4; ++w) s += wsum[w];
        atomicAdd(msum, s);
    }
}

__global__ void k_final(const double* __restrict__ msum,
                        const double* __restrict__ qsum, float* out) {
    if (threadIdx.x == 0) {
        double loss = (*msum) / ((double)BATCH * (double)NTRAIN)
                    + 0.5 * ((*qsum) / ((double)BIT * (double)BATCH));
        out[0] = (float)loss;
    }
}

extern "C" void kernel_launch(void* const* d_in, const int* in_sizes, int n_in,
                              void* d_out, int out_size, void* d_ws, size_t ws_size,
                              hipStream_t stream) {
    const float* u   = (const float*)d_in[0];
    const float* y   = (const float*)d_in[1];
    const int*   ind = (const int*)d_in[2];
    const float* U   = (const float*)d_in[3];
    const float* Y   = (const float*)d_in[4];
    const float* V   = (const float*)d_in[5];
    float* out = (float*)d_out;

    int*   wsI = (int*)d_ws;
    float* wsF = (float*)d_ws;
    int*   owner = wsI + O_OWNER;
    int*   tlab  = wsI + O_TLAB;
    int*   lab   = wsI + O_LAB;
    float* bmat  = wsF + O_BMAT;
    float* Bsum  = wsF + O_BSUM;
    float* count = wsF + O_COUNT;
    double* qsum = (double*)(wsF + O_QSUM);
    double* msum = (double*)(wsF + O_MSUM);

    hipMemsetAsync(owner, 0xFF, NTRAIN * sizeof(int), stream);        // -1
    hipMemsetAsync(wsF + O_QSUM, 0, 4 * sizeof(float), stream);       // qsum,msum

    k_prep<<<1, 512, 0, stream>>>(y, ind, owner, lab);
    k_tlab<<<(NTRAIN + 255) / 256, 256, 0, stream>>>(Y, owner, lab, tlab);
    k_b<<<64, 512, 0, stream>>>(u, V, lab, bmat, qsum);
    k_bsum<<<25, 256, 0, stream>>>(bmat, lab, Bsum, count);
    k_metric<<<(NTRAIN + 255) / 256, 256, 0, stream>>>(u, U, lab, tlab, owner, msum);
    k_gd<<<1, 1024, 0, stream>>>(V, Bsum, count, out);
    k_final<<<1, 64, 0, stream>>>(msum, qsum, out);
}

// Round 3
// 848.759 us; speedup vs baseline: 4.6539x; 3.1553x over previous
//
#include <hip/hip_runtime.h>

#define BIT 64
#define NCLASS 100
#define NTRAIN 100000
#define BATCH 512
// config scalars: MU=1, M=1, ETA=0.5, VUL=1, NTA=1

// ---- workspace element offsets (4-byte slots) ----
#define O_OWNER   0                          // int[100000]
#define O_TLAB    100000                     // int[100000]
#define O_LAB     200000                     // int[512]
#define O_BMAT    200512                     // float[64*512]
#define O_BSUM    233280                     // float[64*100]
#define O_COUNT   239680                     // float[100]
#define O_QSUM    239780                     // double (8B aligned)
#define O_MSUM    239782                     // double

typedef __attribute__((ext_vector_type(8))) short short8v;   // 8 bf16 = 4 VGPR
typedef __attribute__((ext_vector_type(4))) float f32x4;

__device__ __forceinline__ float signf(float x) {
    return (x > 0.f) ? 1.f : ((x < 0.f) ? -1.f : 0.f);
}

// f32 -> bf16 bits, round-nearest-even (unbiased; matters over 200 steps)
__device__ __forceinline__ unsigned short f2bf(float x) {
    union { float f; unsigned u; } v; v.f = x;
    unsigned r = v.u + 0x7FFFu + ((v.u >> 16) & 1u);
    return (unsigned short)(r >> 16);
}
__device__ __forceinline__ unsigned pk2(float a, float b) {
    return (unsigned)f2bf(a) | ((unsigned)f2bf(b) << 16);
}

// labels of the batch + scatter owner map (last-write-wins == max batch idx)
__global__ void k_prep(const float* __restrict__ y, const int* __restrict__ ind,
                       int* owner, int* lab) {
    int b = threadIdx.x;  // 512 threads, 1 block
    const float* row = y + b * NCLASS;
    int best = 0;
    for (int c = 0; c < NCLASS; ++c)
        if (row[c] > 0.5f) best = c;
    lab[b] = best;
    atomicMax(&owner[ind[b]], b);
}

// train labels from one-hot Y, patched by the scatter
__global__ void k_tlab(const float* __restrict__ Y, const int* __restrict__ owner,
                       const int* __restrict__ lab, int* tlab) {
    int j = blockIdx.x * blockDim.x + threadIdx.x;
    if (j >= NTRAIN) return;
    int tl = 0;
    for (int c = 0; c < NCLASS; ++c)
        if (Y[(size_t)c * NTRAIN + j] > 0.5f) tl = c;
    int ow = owner[j];
    tlab[j] = (ow >= 0) ? lab[ow] : tl;
}

// b = sign(MU*sign(V)[:,lab] + u^T)  [64,512], plus quantization-loss sum
__global__ void k_b(const float* __restrict__ u, const float* __restrict__ V,
                    const int* __restrict__ lab, float* bmat, double* qsum) {
    int bb = threadIdx.x;   // 512
    int r  = blockIdx.x;    // 64
    int c = lab[bb];
    float v  = V[r * NCLASS + c];
    float uu = u[bb * BIT + r];
    float t  = signf(v) + uu;            // MU = 1
    float bv = signf(t);
    bmat[r * BATCH + bb] = bv;
    float d = bv - uu;
    double q = (double)(d * d);
    for (int off = 32; off; off >>= 1) q += __shfl_down(q, off);
    __shared__ double wsum[8];
    int wid = threadIdx.x >> 6, lane = threadIdx.x & 63;
    if (lane == 0) wsum[wid] = q;
    __syncthreads();
    if (threadIdx.x == 0) {
        double s = 0;
        for (int w = 0; w < 8; ++w) s += wsum[w];
        atomicAdd(qsum, s);
    }
}

// deterministic per-class accumulation: Bsum[r,c] = sum_{b: lab[b]=c} bmat[r,b]
__global__ void k_bsum(const float* __restrict__ bmat, const int* __restrict__ lab,
                       float* Bsum, float* count) {
    __shared__ int slab[BATCH];
    for (int i = threadIdx.x; i < BATCH; i += blockDim.x) slab[i] = lab[i];
    __syncthreads();
    int idx = blockIdx.x * blockDim.x + threadIdx.x;  // 6400
    if (idx < BIT * NCLASS) {
        int r = idx / NCLASS, c = idx % NCLASS;
        const float* br = bmat + r * BATCH;
        float s = 0.f;
        for (int bb = 0; bb < BATCH; ++bb)
            if (slab[bb] == c) s += br[bb];
        Bsum[idx] = s;
    }
    if (blockIdx.x == 0 && threadIdx.x < NCLASS) {
        int c = threadIdx.x, n = 0;
        for (int bb = 0; bb < BATCH; ++bb)
            if (slab[bb] == c) ++n;
        count[c] = (float)n;
    }
}

// ---------------------------------------------------------------------------
// 200-step GD on V — MFMA version (mfma_f32_16x16x32_bf16), single block.
//
// Fragment-major LDS blobs: [blk][ks][lane][8 bf16], read as one
// lane-consecutive ds_read_b128 (conflict-free).
//   SA: V row-fragments  -> A and B of M = V*V^T (B=V^T frag == A frag of V)
//   SB: V col-fragments  -> B of P = M*V
//   SM: M row-fragments  -> A of P    (written from M-phase D regs as bf16)
// k-element placement uses k=4g+(j&3)+16*(j>>2); any mismatch vs HW cancels
// because BOTH operands of each matmul go through the same formula.
// f32 master V kept per-thread in registers (fixed (m,n) ownership) + VF in
// LDS (rowsum source). 3 barriers/step. Waves 0..13: P+update; 14,15: rowsum.
// ---------------------------------------------------------------------------
#define VFS 116
__global__ __launch_bounds__(1024) void k_gd(const float* __restrict__ V,
                                             const float* __restrict__ Bsum,
                                             const float* __restrict__ count,
                                             float* __restrict__ out) {
    __shared__ unsigned short SA[4 * 4 * 64 * 8];   // 16 KB
    __shared__ unsigned short SB[7 * 2 * 64 * 8];   // 14 KB
    __shared__ unsigned short SM[4 * 2 * 64 * 8];   //  8 KB
    __shared__ float VF[64 * VFS];                  // ~29 KB
    __shared__ float rs[64];

    const int t = threadIdx.x;
    const int l = t & 63;
    const int w = t >> 6;        // wave 0..15
    const int g = l >> 4;        // k-chunk group
    const int c16 = l & 15;

    // zero SA/SB so pad regions (k>=100 cols, n>=100) contribute exactly 0
    for (int i = t; i < 4 * 4 * 64 * 8; i += 1024) SA[i] = 0;
    for (int i = t; i < 7 * 2 * 64 * 8; i += 1024) SB[i] = 0;

    // ---- P/update tile ownership (28 tiles over waves 0..13) ----
    const bool pw = (w < 14);
    int miT[2], njT[2];
    if (w < 12)      { miT[0] = miT[1] = (w & 3); njT[0] = (w >> 2) * 2; njT[1] = njT[0] + 1; }
    else if (w == 12){ miT[0] = 0; miT[1] = 1; njT[0] = njT[1] = 6; }
    else             { miT[0] = 2; miT[1] = 3; njT[0] = njT[1] = 6; }

    float vreg[2][4], bsr[2][4], cntr[2];
    int vfO[2][4], saO[2][4], sbO[2], m0T[2], nT[2];
    bool liveT[2];

    #pragma unroll
    for (int tt = 0; tt < 2; ++tt) {
        const int mi = miT[tt], nj = njT[tt];
        const int m0 = mi * 16 + 4 * g;
        const int n  = nj * 16 + c16;
        m0T[tt] = m0; nT[tt] = n;
        const bool live = pw && (n < NCLASS);
        liveT[tt] = live;
        cntr[tt] = live ? count[n] : 0.f;
        // SB slot: k=m (V row); lane' = g*16 + (n&15) is r-independent -> packable
        sbO[tt] = ((nj * 2 + (mi >> 1)) * 64 + (g * 16 + c16)) * 8 + 4 * (mi & 1);
        #pragma unroll
        for (int r = 0; r < 4; ++r) {
            const int m = m0 + r;
            const int c2 = n & 31;
            vfO[tt][r] = m * VFS + n;
            saO[tt][r] = ((mi * 4 + (n >> 5)) * 64 + (((c2 >> 2) & 3) * 16 + (m & 15))) * 8
                         + (c2 & 3) + 4 * (c2 >> 4);
            const float v = live ? V[m * NCLASS + n] : 0.f;
            vreg[tt][r] = v;
            bsr[tt][r] = live ? Bsum[m * NCLASS + n] : 0.f;
        }
    }

    // ---- M-phase constants: wave w computes tile (mi_m, mj_m) of M ----
    const int mi_m = w >> 2, mj_m = w & 3;
    int smO[4];
    #pragma unroll
    for (int r = 0; r < 4; ++r) {
        const int m = mi_m * 16 + 4 * g + r;        // D row (verified layout)
        const int n = mj_m * 16 + c16;              // D col
        const int c2 = n & 31;
        smO[r] = ((mi_m * 2 + (n >> 5)) * 64 + (((c2 >> 2) & 3) * 16 + (m & 15))) * 8
                 + (c2 & 3) + 4 * (c2 >> 4);
    }

    __syncthreads();   // zeros visible

    // initial fill of VF / SA / SB
    if (pw) {
        #pragma unroll
        for (int tt = 0; tt < 2; ++tt) {
            *(uint2*)&SB[sbO[tt]] =
                make_uint2(pk2(vreg[tt][0], vreg[tt][1]), pk2(vreg[tt][2], vreg[tt][3]));
            #pragma unroll
            for (int r = 0; r < 4; ++r) {
                VF[vfO[tt][r]] = vreg[tt][r];
                SA[saO[tt][r]] = f2bf(vreg[tt][r]);
            }
        }
    }
    __syncthreads();

    const float ci = 2.0f / 32768.0f;   // intra: mean over 64*512
    const float ce = 4.0f / 10000.0f;   // inter (VUL=1): 4/100^2
    const float cq = 2.0f / 6400.0f;    // quant (NTA=1)

    for (int step = 0; step < 200; ++step) {
        float alpha = 0.03f;
        if (step >= 149) alpha *= 0.1f;
        if (step >= 179) alpha *= 0.1f;

        // ---- M = V V^T : one 16x16 tile per wave, K=128 in 4 MFMAs ----
        f32x4 acc = {0.f, 0.f, 0.f, 0.f};
        #pragma unroll
        for (int ks = 0; ks < 4; ++ks) {
            short8v a = *(const short8v*)&SA[((mi_m * 4 + ks) * 64 + l) * 8];
            short8v b = *(const short8v*)&SA[((mj_m * 4 + ks) * 64 + l) * 8];
            acc = __builtin_amdgcn_mfma_f32_16x16x32_bf16(a, b, acc, 0, 0, 0);
        }
        #pragma unroll
        for (int r = 0; r < 4; ++r) SM[smO[r]] = f2bf(acc[r]);
        __syncthreads();

        // ---- P = M V (waves 0..13, 2 tiles each) ; rowsums (waves 14,15) ----
        f32x4 pA = {0.f, 0.f, 0.f, 0.f}, pB = {0.f, 0.f, 0.f, 0.f};
        if (pw) {
            #pragma unroll
            for (int ks = 0; ks < 2; ++ks) {
                short8v a0 = *(const short8v*)&SM[((miT[0] * 2 + ks) * 64 + l) * 8];
                short8v b0 = *(const short8v*)&SB[((njT[0] * 2 + ks) * 64 + l) * 8];
                pA = __builtin_amdgcn_mfma_f32_16x16x32_bf16(a0, b0, pA, 0, 0, 0);
                short8v a1 = *(const short8v*)&SM[((miT[1] * 2 + ks) * 64 + l) * 8];
                short8v b1 = *(const short8v*)&SB[((njT[1] * 2 + ks) * 64 + l) * 8];
                pB = __builtin_amdgcn_mfma_f32_16x16x32_bf16(a1, b1, pB, 0, 0, 0);
            }
        } else {
            const int tt2 = t - 896;           // 0..127
            const int r = tt2 >> 1, h = tt2 & 1;
            float s = 0.f;
            const float* row = &VF[r * VFS + h * 50];
            #pragma unroll 10
            for (int i = 0; i < 50; ++i) s += row[i];
            s += __shfl_xor(s, 1);
            if (h == 0) rs[r] = s;
        }
        __syncthreads();

        // ---- update own 8 elements; refresh VF / SA / SB ----
        if (pw) {
            #pragma unroll
            for (int tt = 0; tt < 2; ++tt) {
                const f32x4 pp = tt ? pB : pA;
                const bool live = liveT[tt];
                const float cnt = cntr[tt];
                float nv[4];
                #pragma unroll
                for (int r = 0; r < 4; ++r) {
                    const float v = vreg[tt][r];
                    const float rsv = rs[m0T[tt] + r];
                    const float gg = ci * (cnt * v - bsr[tt][r])
                                   + ce * (pp[r] - 64.0f * (2.0f * v - rsv))
                                   + cq * (v - signf(v));
                    float vn = v - alpha * gg;
                    vn = live ? vn : 0.f;
                    vreg[tt][r] = vn;
                    nv[r] = vn;
                    VF[vfO[tt][r]] = vn;
                    SA[saO[tt][r]] = f2bf(vn);
                }
                *(uint2*)&SB[sbO[tt]] = make_uint2(pk2(nv[0], nv[1]), pk2(nv[2], nv[3]));
            }
        }
        __syncthreads();
    }

    // write V_new from registers (f32 master copy)
    if (pw) {
        #pragma unroll
        for (int tt = 0; tt < 2; ++tt)
            if (liveT[tt]) {
                #pragma unroll
                for (int r = 0; r < 4; ++r)
                    out[1 + (m0T[tt] + r) * NCLASS + nT[tt]] = vreg[tt][r];
            }
    }
}

// ---------------------------------------------------------------------------
// Metric loss: ip = clip(0.5 * u @ Ueff, -100, 50); softplus; mean.
// ---------------------------------------------------------------------------
__global__ __launch_bounds__(256) void k_metric(const float* __restrict__ u,
                                                const float* __restrict__ U,
                                                const int* __restrict__ lab,
                                                const int* __restrict__ tlab,
                                                const int* __restrict__ owner,
                                                double* msum) {
    __shared__ float ut[64 * 68];   // u^T chunk: ut[r*68 + k]
    __shared__ int slab[BATCH];
    int j = blockIdx.x * blockDim.x + threadIdx.x;

    for (int i = threadIdx.x; i < BATCH; i += 256) slab[i] = lab[i];

    int tl = 0;
    const float* colbase = U;
    size_t cstride = NTRAIN;
    if (j < NTRAIN) {
        tl = tlab[j];
        int ow = owner[j];
        if (ow >= 0) { colbase = u + (size_t)ow * BIT; cstride = 1; }
        else         { colbase = U + j; }
    }

    float lsum = 0.f;
    for (int b0 = 0; b0 < BATCH; b0 += 64) {
        __syncthreads();   // previous chunk's readers done
        for (int i = threadIdx.x; i < 64 * 64; i += 256) {
            int k = i >> 6, r = i & 63;
            ut[r * 68 + k] = u[(b0 + k) * BIT + r];   // coalesced read
        }
        __syncthreads();

        if (j < NTRAIN) {
            float acc[64];
            #pragma unroll
            for (int k = 0; k < 64; ++k) acc[k] = 0.f;
            for (int r = 0; r < BIT; ++r) {
                float Uv = colbase[(size_t)r * cstride];
                const float* urow = &ut[r * 68];
                #pragma unroll
                for (int q = 0; q < 16; ++q) {
                    float4 uv = *(const float4*)&urow[q * 4];
                    acc[4 * q + 0] += uv.x * Uv;
                    acc[4 * q + 1] += uv.y * Uv;
                    acc[4 * q + 2] += uv.z * Uv;
                    acc[4 * q + 3] += uv.w * Uv;
                }
            }
            #pragma unroll
            for (int k = 0; k < 64; ++k) {
                float ip = fminf(fmaxf(0.5f * acc[k], -100.f), 50.f);
                float x = (slab[b0 + k] == tl) ? (1.0f - ip) : (1.0f + ip); // M=1
                lsum += fmaxf(x, 0.f) + __logf(1.f + __expf(-fabsf(x)));
            }
        }
    }

    double d = (double)lsum;
    for (int off = 32; off; off >>= 1) d += __shfl_down(d, off);
    __shared__ double wsum[4];
    int wid = threadIdx.x >> 6, lane = threadIdx.x & 63;
    if (lane == 0) wsum[wid] = d;
    __syncthreads();
    if (threadIdx.x == 0) {
        double s = 0;
        for (int w = 0; w < 4; ++w) s += wsum[w];
        atomicAdd(msum, s);
    }
}

__global__ void k_final(const double* __restrict__ msum,
                        const double* __restrict__ qsum, float* out) {
    if (threadIdx.x == 0) {
        double loss = (*msum) / ((double)BATCH * (double)NTRAIN)
                    + 0.5 * ((*qsum) / ((double)BIT * (double)BATCH));
        out[0] = (float)loss;
    }
}

extern "C" void kernel_launch(void* const* d_in, const int* in_sizes, int n_in,
                              void* d_out, int out_size, void* d_ws, size_t ws_size,
                              hipStream_t stream) {
    const float* u   = (const float*)d_in[0];
    const float* y   = (const float*)d_in[1];
    const int*   ind = (const int*)d_in[2];
    const float* U   = (const float*)d_in[3];
    const float* Y   = (const float*)d_in[4];
    const float* V   = (const float*)d_in[5];
    float* out = (float*)d_out;

    int*   wsI = (int*)d_ws;
    float* wsF = (float*)d_ws;
    int*   owner = wsI + O_OWNER;
    int*   tlab  = wsI + O_TLAB;
    int*   lab   = wsI + O_LAB;
    float* bmat  = wsF + O_BMAT;
    float* Bsum  = wsF + O_BSUM;
    float* count = wsF + O_COUNT;
    double* qsum = (double*)(wsF + O_QSUM);
    double* msum = (double*)(wsF + O_MSUM);

    hipMemsetAsync(owner, 0xFF, NTRAIN * sizeof(int), stream);        // -1
    hipMemsetAsync(wsF + O_QSUM, 0, 4 * sizeof(float), stream);       // qsum,msum

    k_prep<<<1, 512, 0, stream>>>(y, ind, owner, lab);
    k_tlab<<<(NTRAIN + 255) / 256, 256, 0, stream>>>(Y, owner, lab, tlab);
    k_b<<<64, 512, 0, stream>>>(u, V, lab, bmat, qsum);
    k_bsum<<<25, 256, 0, stream>>>(bmat, lab, Bsum, count);
    k_metric<<<(NTRAIN + 255) / 256, 256, 0, stream>>>(u, U, lab, tlab, owner, msum);
    k_gd<<<1, 1024, 0, stream>>>(V, Bsum, count, out);
    k_final<<<1, 64, 0, stream>>>(msum, qsum, out);
}

// Round 4
// 470.745 us; speedup vs baseline: 8.3910x; 1.8030x over previous
//
#include <hip/hip_runtime.h>

#define BIT 64
#define NCLASS 100
#define NTRAIN 100000
#define BATCH 512
// config scalars: MU=1, M=1, ETA=0.5, VUL=1, NTA=1

// ---- workspace element offsets (4-byte slots) ----
#define O_OWNER   0                          // int[100000]
#define O_TLAB    100000                     // int[100000]
#define O_LAB     200000                     // int[512]
#define O_BMAT    200512                     // float[64*512]
#define O_BSUM    233280                     // float[64*100]
#define O_COUNT   239680                     // float[100]
#define O_QSUM    239780                     // double (8B aligned)
#define O_MSUM    239782                     // double

typedef __attribute__((ext_vector_type(8))) short short8v;   // 8 bf16 = 4 VGPR
typedef __attribute__((ext_vector_type(4))) float f32x4;
typedef unsigned short ushortT;

__device__ __forceinline__ float signf(float x) {
    return (x > 0.f) ? 1.f : ((x < 0.f) ? -1.f : 0.f);
}

// f32 -> bf16 bits, round-nearest-even
__device__ __forceinline__ ushortT f2bf(float x) {
    union { float f; unsigned u; } v; v.f = x;
    unsigned r = v.u + 0x7FFFu + ((v.u >> 16) & 1u);
    return (ushortT)(r >> 16);
}
__device__ __forceinline__ unsigned pk2(float a, float b) {
    return (unsigned)f2bf(a) | ((unsigned)f2bf(b) << 16);
}

// labels of the batch + scatter owner map (last-write-wins == max batch idx)
__global__ void k_prep(const float* __restrict__ y, const int* __restrict__ ind,
                       int* owner, int* lab) {
    int b = threadIdx.x;  // 512 threads, 1 block
    const float* row = y + b * NCLASS;
    int best = 0;
    for (int c = 0; c < NCLASS; ++c)
        if (row[c] > 0.5f) best = c;
    lab[b] = best;
    atomicMax(&owner[ind[b]], b);
}

// train labels from one-hot Y, patched by the scatter
__global__ void k_tlab(const float* __restrict__ Y, const int* __restrict__ owner,
                       const int* __restrict__ lab, int* tlab) {
    int j = blockIdx.x * blockDim.x + threadIdx.x;
    if (j >= NTRAIN) return;
    int tl = 0;
    for (int c = 0; c < NCLASS; ++c)
        if (Y[(size_t)c * NTRAIN + j] > 0.5f) tl = c;
    int ow = owner[j];
    tlab[j] = (ow >= 0) ? lab[ow] : tl;
}

// b = sign(MU*sign(V)[:,lab] + u^T)  [64,512], plus quantization-loss sum
__global__ void k_b(const float* __restrict__ u, const float* __restrict__ V,
                    const int* __restrict__ lab, float* bmat, double* qsum) {
    int bb = threadIdx.x;   // 512
    int r  = blockIdx.x;    // 64
    int c = lab[bb];
    float v  = V[r * NCLASS + c];
    float uu = u[bb * BIT + r];
    float t  = signf(v) + uu;            // MU = 1
    float bv = signf(t);
    bmat[r * BATCH + bb] = bv;
    float d = bv - uu;
    double q = (double)(d * d);
    for (int off = 32; off; off >>= 1) q += __shfl_down(q, off);
    __shared__ double wsum[8];
    int wid = threadIdx.x >> 6, lane = threadIdx.x & 63;
    if (lane == 0) wsum[wid] = q;
    __syncthreads();
    if (threadIdx.x == 0) {
        double s = 0;
        for (int w = 0; w < 8; ++w) s += wsum[w];
        atomicAdd(qsum, s);
    }
}

// deterministic per-class accumulation: Bsum[r,c] = sum_{b: lab[b]=c} bmat[r,b]
__global__ void k_bsum(const float* __restrict__ bmat, const int* __restrict__ lab,
                       float* Bsum, float* count) {
    __shared__ int slab[BATCH];
    for (int i = threadIdx.x; i < BATCH; i += blockDim.x) slab[i] = lab[i];
    __syncthreads();
    int idx = blockIdx.x * blockDim.x + threadIdx.x;  // 6400
    if (idx < BIT * NCLASS) {
        int r = idx / NCLASS, c = idx % NCLASS;
        const float* br = bmat + r * BATCH;
        float s = 0.f;
        for (int bb = 0; bb < BATCH; ++bb)
            if (slab[bb] == c) s += br[bb];
        Bsum[idx] = s;
    }
    if (blockIdx.x == 0 && threadIdx.x < NCLASS) {
        int c = threadIdx.x, n = 0;
        for (int bb = 0; bb < BATCH; ++bb)
            if (slab[bb] == c) ++n;
        count[c] = (float)n;
    }
}

// ---------------------------------------------------------------------------
// FUSED kernel: block 0 = 200-step GD on V (1 CU); blocks 1..391 = metric
// loss on the remaining CUs. Independent data -> run concurrently.
//
// GD (512 threads, 8 waves, double-buffered SA/SB -> 2 barriers/step):
//   SA[2]: V row-fragments (A&B of M=V*V^T)  SB[2]: V col-fragments (B of P)
//   SM: M row-fragments (A of P).  rowsum via MFMA with all-ones B-fragment
//   on the 4 diagonal M-tiles (no VF array, no rowsum waves).
//   M-phase: wave w -> tiles (w>>1, (w&1)*2 + {0,1})  [shared A panel]
//   P-phase: wave w -> tiles (mi=w&3, nj=(w+8q)>>2) q=0..3 [shared A panel]
// Metric (512 threads): j = (bid-1)*256 + (t&255); half = t>>8 (256 batch
//   rows each) -> 2x waves vs one-thread-per-column (3+/SIMD occupancy).
// ---------------------------------------------------------------------------
__global__ __launch_bounds__(512, 4) void k_main(
        const float* __restrict__ V, const float* __restrict__ Bsum,
        const float* __restrict__ count, const float* __restrict__ u,
        const float* __restrict__ U, const int* __restrict__ lab,
        const int* __restrict__ tlab, const int* __restrict__ owner,
        double* msum, float* __restrict__ out) {
    __shared__ __align__(16) char smem[69888];

    if (blockIdx.x == 0) {
        // ================= GD =================
        ushortT* SAb = (ushortT*)smem;              // 2 x 8192
        ushortT* SBb = (ushortT*)(smem + 32768);    // 2 x 7168
        ushortT* SMf = (ushortT*)(smem + 61440);    // 4096
        float*   rs  = (float*)(smem + 69632);      // 64

        const int t = threadIdx.x, l = t & 63, w = t >> 6;
        const int g = l >> 4, c16 = l & 15;
        const short8v ONES = {0x3F80,0x3F80,0x3F80,0x3F80,
                              0x3F80,0x3F80,0x3F80,0x3F80};

        for (int i = t; i < 16384; i += 512) SAb[i] = 0;
        for (int i = t; i < 14336; i += 512) SBb[i] = 0;

        // ---- P/update ownership: 4 tile slots, shared mi ----
        const int mi_p = w & 3;
        const int m0 = mi_p * 16 + 4 * g;
        bool wact[4], live[4];
        int pbO[4], sbO[4], nT[4], saO[4][4];
        float vreg[4][4], bsr[4][4], cnt[4];
        #pragma unroll
        for (int q = 0; q < 4; ++q) {
            const int tp = w + 8 * q;
            wact[q] = (tp < 28);
            const int nj = wact[q] ? (tp >> 2) : 0;
            const int n = nj * 16 + c16;
            nT[q] = n;
            live[q] = wact[q] && (n < NCLASS);
            pbO[q] = (nj * 2 * 64 + l) * 8;
            sbO[q] = ((nj * 2 + (mi_p >> 1)) * 64 + (g * 16 + c16)) * 8 + 4 * (mi_p & 1);
            cnt[q] = live[q] ? count[n] : 0.f;
            const int c2 = n & 31;
            #pragma unroll
            for (int r = 0; r < 4; ++r) {
                const int m = m0 + r;
                saO[q][r] = ((mi_p * 4 + (n >> 5)) * 64 + (((c2 >> 2) & 3) * 16 + (m & 15))) * 8
                            + (c2 & 3) + 4 * (c2 >> 4);
                const float v = live[q] ? V[m * NCLASS + n] : 0.f;
                vreg[q][r] = v;
                bsr[q][r] = live[q] ? Bsum[m * NCLASS + n] : 0.f;
            }
        }

        // ---- M-phase constants ----
        const int mi_m = w >> 1, mj0 = (w & 1) * 2, mj1 = mj0 + 1;
        const bool dg0 = (mi_m == mj0), dg1 = (mi_m == mj1);
        const bool dg = dg0 || dg1;
        // SM write base: smO = smB + (mjX>>1)*512 + r*8 + 4*(mjX&1)
        const int smB = (mi_m * 2 * 64 + (c16 >> 2) * 16 + 4 * g) * 8 + (c16 & 3);

        __syncthreads();   // zeros visible

        // initial fill of buffer 0
        #pragma unroll
        for (int q = 0; q < 4; ++q) if (wact[q]) {
            #pragma unroll
            for (int r = 0; r < 4; ++r) SAb[saO[q][r]] = f2bf(vreg[q][r]);
            *(uint2*)&SBb[sbO[q]] =
                make_uint2(pk2(vreg[q][0], vreg[q][1]), pk2(vreg[q][2], vreg[q][3]));
        }
        __syncthreads();

        const float ci = 2.0f / 32768.0f;   // intra
        const float ce = 4.0f / 10000.0f;   // inter (VUL=1)
        const float cq = 2.0f / 6400.0f;    // quant (NTA=1)

        int cur = 0;
        for (int step = 0; step < 200; ++step) {
            float alpha = 0.03f;
            if (step >= 149) alpha *= 0.1f;
            if (step >= 179) alpha *= 0.1f;

            const ushortT* SAc = SAb + cur * 8192;

            // ---- M = V V^T (2 tiles, shared A) + rowsum via ones-MFMA ----
            f32x4 aM0 = {0.f,0.f,0.f,0.f}, aM1 = {0.f,0.f,0.f,0.f};
            f32x4 aR  = {0.f,0.f,0.f,0.f};
            #pragma unroll
            for (int ks = 0; ks < 4; ++ks) {
                short8v a  = *(const short8v*)&SAc[((mi_m * 4 + ks) * 64 + l) * 8];
                short8v b0 = *(const short8v*)&SAc[((mj0 * 4 + ks) * 64 + l) * 8];
                short8v b1 = *(const short8v*)&SAc[((mj1 * 4 + ks) * 64 + l) * 8];
                aM0 = __builtin_amdgcn_mfma_f32_16x16x32_bf16(a, b0, aM0, 0, 0, 0);
                aM1 = __builtin_amdgcn_mfma_f32_16x16x32_bf16(a, b1, aM1, 0, 0, 0);
                if (dg)
                    aR = __builtin_amdgcn_mfma_f32_16x16x32_bf16(a, ONES, aR, 0, 0, 0);
            }
            #pragma unroll
            for (int r = 0; r < 4; ++r) {
                SMf[smB + (mj0 >> 1) * 512 + r * 8 + 4 * (mj0 & 1)] = f2bf(aM0[r]);
                SMf[smB + (mj1 >> 1) * 512 + r * 8 + 4 * (mj1 & 1)] = f2bf(aM1[r]);
            }
            if (dg && c16 == 0) {
                #pragma unroll
                for (int r = 0; r < 4; ++r) rs[mi_m * 16 + 4 * g + r] = aR[r];
            }
            __syncthreads();

            // ---- P = M V (4 tiles, shared A) ----
            const ushortT* SBc = SBb + cur * 7168;
            f32x4 p[4];
            #pragma unroll
            for (int q = 0; q < 4; ++q) p[q] = (f32x4){0.f,0.f,0.f,0.f};
            #pragma unroll
            for (int ks = 0; ks < 2; ++ks) {
                short8v aP = *(const short8v*)&SMf[((mi_p * 2 + ks) * 64 + l) * 8];
                #pragma unroll
                for (int q = 0; q < 4; ++q) if (wact[q]) {
                    short8v bP = *(const short8v*)&SBc[pbO[q] + ks * 512];
                    p[q] = __builtin_amdgcn_mfma_f32_16x16x32_bf16(aP, bP, p[q], 0, 0, 0);
                }
            }
            float rsv[4];
            #pragma unroll
            for (int r = 0; r < 4; ++r) rsv[r] = rs[m0 + r];

            // ---- update own elements into the NEXT buffers ----
            const int nxt = cur ^ 1;
            ushortT* SAn = SAb + nxt * 8192;
            ushortT* SBn = SBb + nxt * 7168;
            #pragma unroll
            for (int q = 0; q < 4; ++q) if (wact[q]) {
                float nv[4];
                #pragma unroll
                for (int r = 0; r < 4; ++r) {
                    const float v = vreg[q][r];
                    const float gg = ci * (cnt[q] * v - bsr[q][r])
                                   + ce * (p[q][r] - 64.0f * (2.0f * v - rsv[r]))
                                   + cq * (v - signf(v));
                    float vn = v - alpha * gg;
                    vn = live[q] ? vn : 0.f;
                    vreg[q][r] = vn;
                    nv[r] = vn;
                    SAn[saO[q][r]] = f2bf(vn);
                }
                *(uint2*)&SBn[sbO[q]] = make_uint2(pk2(nv[0], nv[1]), pk2(nv[2], nv[3]));
            }
            __syncthreads();
            cur = nxt;
        }

        // write V_new from f32 register master copy
        #pragma unroll
        for (int q = 0; q < 4; ++q) if (live[q]) {
            #pragma unroll
            for (int r = 0; r < 4; ++r)
                out[1 + (m0 + r) * NCLASS + nT[q]] = vreg[q][r];
        }
    } else {
        // ================= metric =================
        float* ut   = (float*)smem;                 // [2][64*68]
        int*   slab = (int*)(smem + 34816);         // [512]
        double* wsum = (double*)(smem + 36864);     // [8]

        const int t = threadIdx.x;
        const int j = (blockIdx.x - 1) * 256 + (t & 255);
        const int half = t >> 8;
        slab[t] = lab[t];

        int tl = 0;
        const float* colbase = U;
        size_t cstride = NTRAIN;
        const bool jok = (j < NTRAIN);
        if (jok) {
            tl = tlab[j];
            int ow = owner[j];
            if (ow >= 0) { colbase = u + (size_t)ow * BIT; cstride = 1; }
            else         { colbase = U + j; }
        }

        float lsum = 0.f;
        for (int ci = 0; ci < 4; ++ci) {
            __syncthreads();   // previous chunk's readers done (also covers slab)
            for (int i = t; i < 8192; i += 512) {
                int buf = i >> 12, k = (i >> 6) & 63, r = i & 63;
                ut[buf * 4352 + r * 68 + k] = u[((buf * 4 + ci) * 64 + k) * BIT + r];
            }
            __syncthreads();

            if (jok) {
                const float* myut = ut + half * 4352;
                float acc[64];
                #pragma unroll
                for (int k = 0; k < 64; ++k) acc[k] = 0.f;
                #pragma unroll 2
                for (int r = 0; r < BIT; ++r) {
                    float Uv = colbase[(size_t)r * cstride];
                    const float* urow = &myut[r * 68];
                    #pragma unroll
                    for (int qq = 0; qq < 16; ++qq) {
                        float4 uv = *(const float4*)&urow[qq * 4];
                        acc[4 * qq + 0] += uv.x * Uv;
                        acc[4 * qq + 1] += uv.y * Uv;
                        acc[4 * qq + 2] += uv.z * Uv;
                        acc[4 * qq + 3] += uv.w * Uv;
                    }
                }
                const int b0 = (half * 4 + ci) * 64;
                #pragma unroll
                for (int k = 0; k < 64; ++k) {
                    float ip = fminf(fmaxf(0.5f * acc[k], -100.f), 50.f);
                    float x = (slab[b0 + k] == tl) ? (1.0f - ip) : (1.0f + ip); // M=1
                    lsum += fmaxf(x, 0.f) + __logf(1.f + __expf(-fabsf(x)));
                }
            }
        }

        double d = (double)lsum;
        for (int off = 32; off; off >>= 1) d += __shfl_down(d, off);
        const int wid = t >> 6, lane = t & 63;
        if (lane == 0) wsum[wid] = d;
        __syncthreads();
        if (t == 0) {
            double s = 0;
            for (int ww = 0; ww < 8; ++ww) s += wsum[ww];
            atomicAdd(msum, s);
        }
    }
}

__global__ void k_final(const double* __restrict__ msum,
                        const double* __restrict__ qsum, float* out) {
    if (threadIdx.x == 0) {
        double loss = (*msum) / ((double)BATCH * (double)NTRAIN)
                    + 0.5 * ((*qsum) / ((double)BIT * (double)BATCH));
        out[0] = (float)loss;
    }
}

extern "C" void kernel_launch(void* const* d_in, const int* in_sizes, int n_in,
                              void* d_out, int out_size, void* d_ws, size_t ws_size,
                              hipStream_t stream) {
    const float* u   = (const float*)d_in[0];
    const float* y   = (const float*)d_in[1];
    const int*   ind = (const int*)d_in[2];
    const float* U   = (const float*)d_in[3];
    const float* Y   = (const float*)d_in[4];
    const float* V   = (const float*)d_in[5];
    float* out = (float*)d_out;

    int*   wsI = (int*)d_ws;
    float* wsF = (float*)d_ws;
    int*   owner = wsI + O_OWNER;
    int*   tlab  = wsI + O_TLAB;
    int*   lab   = wsI + O_LAB;
    float* bmat  = wsF + O_BMAT;
    float* Bsum  = wsF + O_BSUM;
    float* count = wsF + O_COUNT;
    double* qsum = (double*)(wsF + O_QSUM);
    double* msum = (double*)(wsF + O_MSUM);

    hipMemsetAsync(owner, 0xFF, NTRAIN * sizeof(int), stream);        // -1
    hipMemsetAsync(wsF + O_QSUM, 0, 4 * sizeof(float), stream);       // qsum,msum

    k_prep<<<1, 512, 0, stream>>>(y, ind, owner, lab);
    k_tlab<<<(NTRAIN + 255) / 256, 256, 0, stream>>>(Y, owner, lab, tlab);
    k_b<<<64, 512, 0, stream>>>(u, V, lab, bmat, qsum);
    k_bsum<<<25, 256, 0, stream>>>(bmat, lab, Bsum, count);
    k_main<<<1 + (NTRAIN + 255) / 256, 512, 0, stream>>>(
        V, Bsum, count, u, U, lab, tlab, owner, msum, out);
    k_final<<<1, 64, 0, stream>>>(msum, qsum, out);
}

// Round 5
// 406.902 us; speedup vs baseline: 9.7076x; 1.1569x over previous
//
#include <hip/hip_runtime.h>

#define BIT 64
#define NCLASS 100
#define NTRAIN 100000
#define BATCH 512
// config scalars: MU=1, M=1, ETA=0.5, VUL=1, NTA=1

// ---- workspace element offsets (4-byte slots) ----
#define O_OWNER   0                          // int[100000]
#define O_TLAB    100000                     // int[100000]
#define O_LAB     200000                     // int[512]
#define O_BMAT    200512                     // float[64*512]
#define O_BSUM    233280                     // float[64*100]
#define O_COUNT   239680                     // float[100]
#define O_QSUM    239780                     // double (8B aligned)
#define O_MSUM    239782                     // double

typedef __attribute__((ext_vector_type(8))) short short8v;   // 8 bf16 = 4 VGPR
typedef __attribute__((ext_vector_type(4))) float f32x4;
typedef unsigned short ushortT;

__device__ __forceinline__ float signf(float x) {
    return (x > 0.f) ? 1.f : ((x < 0.f) ? -1.f : 0.f);
}

// f32 -> bf16 bits, round-nearest-even
__device__ __forceinline__ ushortT f2bf(float x) {
    union { float f; unsigned u; } v; v.f = x;
    unsigned r = v.u + 0x7FFFu + ((v.u >> 16) & 1u);
    return (ushortT)(r >> 16);
}
__device__ __forceinline__ unsigned pk2(float a, float b) {
    return (unsigned)f2bf(a) | ((unsigned)f2bf(b) << 16);
}

// labels of the batch + scatter owner map (last-write-wins == max batch idx)
__global__ void k_prep(const float* __restrict__ y, const int* __restrict__ ind,
                       int* owner, int* lab) {
    int b = threadIdx.x;  // 512 threads, 1 block
    const float* row = y + b * NCLASS;
    int best = 0;
    for (int c = 0; c < NCLASS; ++c)
        if (row[c] > 0.5f) best = c;
    lab[b] = best;
    atomicMax(&owner[ind[b]], b);
}

// train labels from one-hot Y, patched by the scatter
__global__ void k_tlab(const float* __restrict__ Y, const int* __restrict__ owner,
                       const int* __restrict__ lab, int* tlab) {
    int j = blockIdx.x * blockDim.x + threadIdx.x;
    if (j >= NTRAIN) return;
    int tl = 0;
    for (int c = 0; c < NCLASS; ++c)
        if (Y[(size_t)c * NTRAIN + j] > 0.5f) tl = c;
    int ow = owner[j];
    tlab[j] = (ow >= 0) ? lab[ow] : tl;
}

// b = sign(MU*sign(V)[:,lab] + u^T)  [64,512], plus quantization-loss sum
__global__ void k_b(const float* __restrict__ u, const float* __restrict__ V,
                    const int* __restrict__ lab, float* bmat, double* qsum) {
    int bb = threadIdx.x;   // 512
    int r  = blockIdx.x;    // 64
    int c = lab[bb];
    float v  = V[r * NCLASS + c];
    float uu = u[bb * BIT + r];
    float t  = signf(v) + uu;            // MU = 1
    float bv = signf(t);
    bmat[r * BATCH + bb] = bv;
    float d = bv - uu;
    double q = (double)(d * d);
    for (int off = 32; off; off >>= 1) q += __shfl_down(q, off);
    __shared__ double wsum[8];
    int wid = threadIdx.x >> 6, lane = threadIdx.x & 63;
    if (lane == 0) wsum[wid] = q;
    __syncthreads();
    if (threadIdx.x == 0) {
        double s = 0;
        for (int w = 0; w < 8; ++w) s += wsum[w];
        atomicAdd(qsum, s);
    }
}

// deterministic per-class accumulation: Bsum[r,c] = sum_{b: lab[b]=c} bmat[r,b]
__global__ void k_bsum(const float* __restrict__ bmat, const int* __restrict__ lab,
                       float* Bsum, float* count) {
    __shared__ int slab[BATCH];
    for (int i = threadIdx.x; i < BATCH; i += blockDim.x) slab[i] = lab[i];
    __syncthreads();
    int idx = blockIdx.x * blockDim.x + threadIdx.x;  // 6400
    if (idx < BIT * NCLASS) {
        int r = idx / NCLASS, c = idx % NCLASS;
        const float* br = bmat + r * BATCH;
        float s = 0.f;
        for (int bb = 0; bb < BATCH; ++bb)
            if (slab[bb] == c) s += br[bb];
        Bsum[idx] = s;
    }
    if (blockIdx.x == 0 && threadIdx.x < NCLASS) {
        int c = threadIdx.x, n = 0;
        for (int bb = 0; bb < BATCH; ++bb)
            if (slab[bb] == c) ++n;
        count[c] = (float)n;
    }
}

// ---------------------------------------------------------------------------
// FUSED kernel: block 0 = 200-step GD on V (1 CU); blocks 1..391 = metric.
//
// GD (512 thr, 8 waves, dbuf SA/SB, 2 barriers/step), P computed TRANSPOSED:
//   M-phase : M = V*V^T  (A,B from SA; wave w -> tiles (w>>1, 2(w&1)+{0,1}));
//             rowsum via ones-MFMA on waves {0,2,5,7}. SM/rs writes own-lane
//             contiguous b64/b128 (conflict-free).
//   P-phase : P^T = V^T * M   (A = SB fragments — same slot formula as B of
//             M*V, so SB is reused unchanged; B = SM). Thread owns 1 bit-row
//             m, 4 consecutive classes n  ->  SA update = 1 b64 (own lane!),
//             SB update = 4 b16 at 2-way (free), vs R4's 32-way scatter.
//   update  : vn = v - alpha*(K*v + ncib + ce*p + 64ce*rs - copysign(cq,v)),
//             K/ncib precomputed per element; only alpha is step-dependent.
// ---------------------------------------------------------------------------
__global__ __launch_bounds__(512, 4) void k_main(
        const float* __restrict__ V, const float* __restrict__ Bsum,
        const float* __restrict__ count, const float* __restrict__ u,
        const float* __restrict__ U, const int* __restrict__ lab,
        const int* __restrict__ tlab, const int* __restrict__ owner,
        double* msum, float* __restrict__ out) {
    __shared__ __align__(16) char smem[69888];

    if (blockIdx.x == 0) {
        // ================= GD =================
        ushortT* SAb = (ushortT*)smem;              // 2 x 8192 shorts (32 KB)
        ushortT* SBb = (ushortT*)(smem + 32768);    // 2 x 7168 shorts (28 KB)
        ushortT* SMf = (ushortT*)(smem + 61440);    // 4096 shorts (8 KB)
        float*   rs  = (float*)(smem + 69632);      // 64 floats

        const int t = threadIdx.x, l = t & 63, w = t >> 6;
        const int g = l >> 4, c16 = l & 15;
        const short8v ONES = {0x3F80,0x3F80,0x3F80,0x3F80,
                              0x3F80,0x3F80,0x3F80,0x3F80};

        for (int i = t; i < 16384; i += 512) SAb[i] = 0;
        for (int i = t; i < 14336; i += 512) SBb[i] = 0;

        const float ci = 2.0f / 32768.0f;   // intra: mean over 64*512
        const float ce = 4.0f / 10000.0f;   // inter (VUL=1): 4/100^2
        const float cq = 2.0f / 6400.0f;    // quant (NTA=1)
        const float ce64 = 64.0f * ce;

        // ---- ownership: thread owns bit-row m, 4 classes per q-slot ----
        const int mtile = w & 3;
        const int m = mtile * 16 + c16;
        bool wact[4], live[4];
        int ntile[4], saO[4], sbO[4];
        float vreg[4][4], Kc[4][4], ncib[4][4];
        #pragma unroll
        for (int q = 0; q < 4; ++q) {
            const int tp = w + 8 * q;
            wact[q] = (tp < 28);
            const int nt = wact[q] ? (tp >> 2) : 0;
            ntile[q] = nt;
            const int n0 = nt * 16 + 4 * g;
            live[q] = wact[q] && (n0 < NCLASS);
            // SA: A-frag of M. slot lane == own lane, j = r + 4*(nt&1)
            saO[q] = ((mtile * 4 + (nt >> 1)) * 64 + l) * 8 + 4 * (nt & 1);
            // SB: A-frag of P^T / B-frag of M*V. element r at sbO + r*8
            sbO[q] = ((nt * 2 + (mtile >> 1)) * 64 + (4 * g + 16 * (c16 >> 2))) * 8
                     + (c16 & 3) + 4 * (mtile & 1);
            #pragma unroll
            for (int r = 0; r < 4; ++r) {
                float v = 0.f, bs = 0.f, cn = 0.f;
                if (live[q]) {
                    const int n = n0 + r;
                    v  = V[m * NCLASS + n];
                    bs = Bsum[m * NCLASS + n];
                    cn = count[n];
                }
                vreg[q][r] = v;
                Kc[q][r]   = ci * cn + cq - 128.f * ce;
                ncib[q][r] = -ci * bs;
            }
        }

        // ---- M-phase constants ----
        const int mi_m = w >> 1, mj0 = (w & 1) * 2, mj1 = mj0 + 1;
        const bool dg = (mi_m == mj0) || (mi_m == mj1);   // waves 0,2,5,7
        const int smO0 = ((mj0 * 2 + (mi_m >> 1)) * 64 + l) * 8 + 4 * (mi_m & 1);
        const int smO1 = ((mj1 * 2 + (mi_m >> 1)) * 64 + l) * 8 + 4 * (mi_m & 1);

        __syncthreads();   // zeros visible

        // initial fill of buffer 0
        #pragma unroll
        for (int q = 0; q < 4; ++q) if (wact[q]) {
            *(uint2*)&SAb[saO[q]] =
                make_uint2(pk2(vreg[q][0], vreg[q][1]), pk2(vreg[q][2], vreg[q][3]));
            #pragma unroll
            for (int r = 0; r < 4; ++r) SBb[sbO[q] + r * 8] = f2bf(vreg[q][r]);
        }
        __syncthreads();

        int cur = 0;
        for (int step = 0; step < 200; ++step) {
            float alpha = 0.03f;
            if (step >= 149) alpha *= 0.1f;
            if (step >= 179) alpha *= 0.1f;

            const ushortT* SAc = SAb + cur * 8192;

            // ---- M = V V^T (2 tiles, shared A) + rowsum ones-MFMA ----
            f32x4 aM0 = {0.f,0.f,0.f,0.f}, aM1 = {0.f,0.f,0.f,0.f};
            f32x4 aR  = {0.f,0.f,0.f,0.f};
            #pragma unroll
            for (int ks = 0; ks < 4; ++ks) {
                short8v a  = *(const short8v*)&SAc[((mi_m * 4 + ks) * 64 + l) * 8];
                short8v b0 = *(const short8v*)&SAc[((mj0 * 4 + ks) * 64 + l) * 8];
                short8v b1 = *(const short8v*)&SAc[((mj1 * 4 + ks) * 64 + l) * 8];
                aM0 = __builtin_amdgcn_mfma_f32_16x16x32_bf16(a, b0, aM0, 0, 0, 0);
                aM1 = __builtin_amdgcn_mfma_f32_16x16x32_bf16(a, b1, aM1, 0, 0, 0);
                if (dg)
                    aR = __builtin_amdgcn_mfma_f32_16x16x32_bf16(a, ONES, aR, 0, 0, 0);
            }
            // SM writes: own lane, contiguous j -> one b64 each, conflict-free
            *(uint2*)&SMf[smO0] = make_uint2(pk2(aM0[0], aM0[1]), pk2(aM0[2], aM0[3]));
            *(uint2*)&SMf[smO1] = make_uint2(pk2(aM1[0], aM1[1]), pk2(aM1[2], aM1[3]));
            if (dg && c16 == 0)
                *(f32x4*)&rs[mi_m * 16 + 4 * g] = aR;
            __syncthreads();

            // ---- P^T = V^T M (4 tiles, shared B = SM[mtile]) ----
            const ushortT* SBc = SBb + cur * 7168;
            f32x4 p[4];
            #pragma unroll
            for (int q = 0; q < 4; ++q) p[q] = (f32x4){0.f,0.f,0.f,0.f};
            #pragma unroll
            for (int kb = 0; kb < 2; ++kb) {
                short8v bP = *(const short8v*)&SMf[((mtile * 2 + kb) * 64 + l) * 8];
                #pragma unroll
                for (int q = 0; q < 4; ++q) if (wact[q]) {
                    short8v aP = *(const short8v*)&SBc[((ntile[q] * 2 + kb) * 64 + l) * 8];
                    p[q] = __builtin_amdgcn_mfma_f32_16x16x32_bf16(aP, bP, p[q], 0, 0, 0);
                }
            }
            const float rsm = rs[m];

            // ---- update into NEXT buffers ----
            const int nxt = cur ^ 1;
            ushortT* SAn = SAb + nxt * 8192;
            ushortT* SBn = SBb + nxt * 7168;
            #pragma unroll
            for (int q = 0; q < 4; ++q) if (wact[q]) {
                float nv[4];
                #pragma unroll
                for (int r = 0; r < 4; ++r) {
                    const float v = vreg[q][r];
                    float t1 = __builtin_fmaf(Kc[q][r], v, ncib[q][r]);
                    t1 = __builtin_fmaf(ce,   p[q][r], t1);
                    t1 = __builtin_fmaf(ce64, rsm,     t1);
                    t1 -= __builtin_copysignf(cq, v);
                    float vn = __builtin_fmaf(-alpha, t1, v);
                    vn = live[q] ? vn : 0.f;
                    vreg[q][r] = vn;
                    nv[r] = vn;
                }
                *(uint2*)&SAn[saO[q]] =
                    make_uint2(pk2(nv[0], nv[1]), pk2(nv[2], nv[3]));
                #pragma unroll
                for (int r = 0; r < 4; ++r) SBn[sbO[q] + r * 8] = f2bf(nv[r]);
            }
            __syncthreads();
            cur = nxt;
        }

        // write V_new from f32 register master copy
        #pragma unroll
        for (int q = 0; q < 4; ++q) if (live[q]) {
            const int n0 = ntile[q] * 16 + 4 * g;
            #pragma unroll
            for (int r = 0; r < 4; ++r)
                out[1 + m * NCLASS + n0 + r] = vreg[q][r];
        }
    } else {
        // ================= metric =================
        float* ut   = (float*)smem;                 // [2][64*68]
        int*   slab = (int*)(smem + 34816);         // [512]
        double* wsum = (double*)(smem + 36864);     // [8]

        const int t = threadIdx.x;
        const int j = (blockIdx.x - 1) * 256 + (t & 255);
        const int half = t >> 8;
        slab[t] = lab[t];

        int tl = 0;
        const float* colbase = U;
        size_t cstride = NTRAIN;
        const bool jok = (j < NTRAIN);
        if (jok) {
            tl = tlab[j];
            int ow = owner[j];
            if (ow >= 0) { colbase = u + (size_t)ow * BIT; cstride = 1; }
            else         { colbase = U + j; }
        }

        float lsum = 0.f;
        for (int ci = 0; ci < 4; ++ci) {
            __syncthreads();   // previous chunk's readers done (also covers slab)
            for (int i = t; i < 8192; i += 512) {
                int buf = i >> 12, k = (i >> 6) & 63, r = i & 63;
                ut[buf * 4352 + r * 68 + k] = u[((buf * 4 + ci) * 64 + k) * BIT + r];
            }
            __syncthreads();

            if (jok) {
                const float* myut = ut + half * 4352;
                float acc[64];
                #pragma unroll
                for (int k = 0; k < 64; ++k) acc[k] = 0.f;
                #pragma unroll 2
                for (int r = 0; r < BIT; ++r) {
                    float Uv = colbase[(size_t)r * cstride];
                    const float* urow = &myut[r * 68];
                    #pragma unroll
                    for (int qq = 0; qq < 16; ++qq) {
                        float4 uv = *(const float4*)&urow[qq * 4];
                        acc[4 * qq + 0] += uv.x * Uv;
                        acc[4 * qq + 1] += uv.y * Uv;
                        acc[4 * qq + 2] += uv.z * Uv;
                        acc[4 * qq + 3] += uv.w * Uv;
                    }
                }
                const int b0 = (half * 4 + ci) * 64;
                #pragma unroll
                for (int k = 0; k < 64; ++k) {
                    float ip = fminf(fmaxf(0.5f * acc[k], -100.f), 50.f);
                    float x = (slab[b0 + k] == tl) ? (1.0f - ip) : (1.0f + ip); // M=1
                    lsum += fmaxf(x, 0.f) + __logf(1.f + __expf(-fabsf(x)));
                }
            }
        }

        double d = (double)lsum;
        for (int off = 32; off; off >>= 1) d += __shfl_down(d, off);
        const int wid = t >> 6, lane = t & 63;
        if (lane == 0) wsum[wid] = d;
        __syncthreads();
        if (t == 0) {
            double s = 0;
            for (int ww = 0; ww < 8; ++ww) s += wsum[ww];
            atomicAdd(msum, s);
        }
    }
}

__global__ void k_final(const double* __restrict__ msum,
                        const double* __restrict__ qsum, float* out) {
    if (threadIdx.x == 0) {
        double loss = (*msum) / ((double)BATCH * (double)NTRAIN)
                    + 0.5 * ((*qsum) / ((double)BIT * (double)BATCH));
        out[0] = (float)loss;
    }
}

extern "C" void kernel_launch(void* const* d_in, const int* in_sizes, int n_in,
                              void* d_out, int out_size, void* d_ws, size_t ws_size,
                              hipStream_t stream) {
    const float* u   = (const float*)d_in[0];
    const float* y   = (const float*)d_in[1];
    const int*   ind = (const int*)d_in[2];
    const float* U   = (const float*)d_in[3];
    const float* Y   = (const float*)d_in[4];
    const float* V   = (const float*)d_in[5];
    float* out = (float*)d_out;

    int*   wsI = (int*)d_ws;
    float* wsF = (float*)d_ws;
    int*   owner = wsI + O_OWNER;
    int*   tlab  = wsI + O_TLAB;
    int*   lab   = wsI + O_LAB;
    float* bmat  = wsF + O_BMAT;
    float* Bsum  = wsF + O_BSUM;
    float* count = wsF + O_COUNT;
    double* qsum = (double*)(wsF + O_QSUM);
    double* msum = (double*)(wsF + O_MSUM);

    hipMemsetAsync(owner, 0xFF, NTRAIN * sizeof(int), stream);        // -1
    hipMemsetAsync(wsF + O_QSUM, 0, 4 * sizeof(float), stream);       // qsum,msum

    k_prep<<<1, 512, 0, stream>>>(y, ind, owner, lab);
    k_tlab<<<(NTRAIN + 255) / 256, 256, 0, stream>>>(Y, owner, lab, tlab);
    k_b<<<64, 512, 0, stream>>>(u, V, lab, bmat, qsum);
    k_bsum<<<25, 256, 0, stream>>>(bmat, lab, Bsum, count);
    k_main<<<1 + (NTRAIN + 255) / 256, 512, 0, stream>>>(
        V, Bsum, count, u, U, lab, tlab, owner, msum, out);
    k_final<<<1, 64, 0, stream>>>(msum, qsum, out);
}

// Round 6
// 392.346 us; speedup vs baseline: 10.0678x; 1.0371x over previous
//
#include <hip/hip_runtime.h>

#define BIT 64
#define NCLASS 100
#define NTRAIN 100000
#define BATCH 512
// config scalars: MU=1, M=1, ETA=0.5, VUL=1, NTA=1

// ---- workspace element offsets (4-byte slots) ----
#define O_OWNER   0                          // int[100000]
#define O_LAB     200000                     // int[512]
#define O_BMAT    200512                     // float[64*512]
#define O_BSUM    233280                     // float[64*100]
#define O_COUNT   239680                     // float[100]
#define O_QSUM    239780                     // double (8B aligned)
#define O_MSUM    239782                     // double

typedef __attribute__((ext_vector_type(8))) short short8v;   // 8 bf16 = 4 VGPR
typedef __attribute__((ext_vector_type(4))) float f32x4;
typedef unsigned short ushortT;

__device__ __forceinline__ float signf(float x) {
    return (x > 0.f) ? 1.f : ((x < 0.f) ? -1.f : 0.f);
}

// one-instr bf16 pack: lo -> bits[15:0], hi -> bits[31:16]
__device__ __forceinline__ unsigned cvtpk(float lo, float hi) {
    unsigned r;
    asm("v_cvt_pk_bf16_f32 %0, %1, %2" : "=v"(r) : "v"(lo), "v"(hi));
    return r;
}
// quad_perm DPP lane exchanges (pure VALU, no LDS pipe)
__device__ __forceinline__ float dpp_x1(float x) {   // lane ^= 1
    union { float f; int i; } v; v.f = x;
    v.i = __builtin_amdgcn_mov_dpp(v.i, 0xB1, 0xF, 0xF, false);
    return v.f;
}
__device__ __forceinline__ float dpp_x2(float x) {   // lane ^= 2
    union { float f; int i; } v; v.f = x;
    v.i = __builtin_amdgcn_mov_dpp(v.i, 0x4E, 0xF, 0xF, false);
    return v.f;
}

// labels of the batch + scatter owner map (last-write-wins == max batch idx)
__global__ void k_prep(const float* __restrict__ y, const int* __restrict__ ind,
                       int* owner, int* lab) {
    int b = threadIdx.x;  // 512 threads, 1 block
    const float* row = y + b * NCLASS;
    int best = 0;
    for (int c = 0; c < NCLASS; ++c)
        if (row[c] > 0.5f) best = c;
    lab[b] = best;
    atomicMax(&owner[ind[b]], b);
}

// b = sign(MU*sign(V)[:,lab] + u^T)  [64,512], plus quantization-loss sum
__global__ void k_b(const float* __restrict__ u, const float* __restrict__ V,
                    const int* __restrict__ lab, float* bmat, double* qsum) {
    int bb = threadIdx.x;   // 512
    int r  = blockIdx.x;    // 64
    int c = lab[bb];
    float v  = V[r * NCLASS + c];
    float uu = u[bb * BIT + r];
    float t  = signf(v) + uu;            // MU = 1
    float bv = signf(t);
    bmat[r * BATCH + bb] = bv;
    float d = bv - uu;
    double q = (double)(d * d);
    for (int off = 32; off; off >>= 1) q += __shfl_down(q, off);
    __shared__ double wsum[8];
    int wid = threadIdx.x >> 6, lane = threadIdx.x & 63;
    if (lane == 0) wsum[wid] = q;
    __syncthreads();
    if (threadIdx.x == 0) {
        double s = 0;
        for (int w = 0; w < 8; ++w) s += wsum[w];
        atomicAdd(qsum, s);
    }
}

// deterministic per-class accumulation: Bsum[r,c] = sum_{b: lab[b]=c} bmat[r,b]
__global__ void k_bsum(const float* __restrict__ bmat, const int* __restrict__ lab,
                       float* Bsum, float* count) {
    __shared__ int slab[BATCH];
    for (int i = threadIdx.x; i < BATCH; i += blockDim.x) slab[i] = lab[i];
    __syncthreads();
    int idx = blockIdx.x * blockDim.x + threadIdx.x;  // 6400
    if (idx < BIT * NCLASS) {
        int r = idx / NCLASS, c = idx % NCLASS;
        const float* br = bmat + r * BATCH;
        float s = 0.f;
        for (int bb = 0; bb < BATCH; ++bb)
            if (slab[bb] == c) s += br[bb];
        Bsum[idx] = s;
    }
    if (blockIdx.x == 0 && threadIdx.x < NCLASS) {
        int c = threadIdx.x, n = 0;
        for (int bb = 0; bb < BATCH; ++bb)
            if (slab[bb] == c) ++n;
        count[c] = (float)n;
    }
}

// ---------------------------------------------------------------------------
// FUSED kernel: block 0 = 200-step GD on V (1 CU); blocks 1..391 = metric
// (which also computes its own tlab slice from Y — k_tlab launch removed).
//
// GD (512 thr, 8 waves, dbuf SA/SB, 2 barriers/step), write-path redesign:
//   M-phase : wave (h = w>>2, mtile = w&3) computes the VERTICAL tile pair
//             (2h, mtile), (2h+1, mtile) sharing B = SA[mtile]. Both tiles'
//             D rows land in SM panel (mtile, h) at j=0..3 / 4..7 -> ONE
//             conflict-free b128 SM write (was 2x b64 @ 8-way).
//             Rowsum via ones-MFMA on waves with mtile>>1 == h (A = b panel).
//   P-phase : P^T = V^T * M; thread owns (1 m, 4 n) per q-slot, nt = 4h+q ->
//             q-pairs share one SA ks chunk: SA update = TWO b128 at own
//             lane (was 4x b64 @ 8-way).
//   SB      : in-register 4x4 quad transpose (2 DPP quad_perm stages) turns
//             each lane's (1 m, 4 n) into a (4 m, 1 n) column -> ONE b64
//             per q (was 4 scattered b16 @ ~16-way).
//   k-placement k = 32kb + 16(j>>2) + 4g + (j&3) identical on both operand
//   sides of each matmul (pi-cancellation, carried from R3-R5 verified).
// ---------------------------------------------------------------------------
__global__ __launch_bounds__(512, 4) void k_main(
        const float* __restrict__ V, const float* __restrict__ Bsum,
        const float* __restrict__ count, const float* __restrict__ u,
        const float* __restrict__ U, const float* __restrict__ Y,
        const int* __restrict__ lab, const int* __restrict__ owner,
        double* msum, float* __restrict__ out) {
    __shared__ __align__(16) char smem[69888];

    if (blockIdx.x == 0) {
        // ================= GD =================
        ushortT* SAb = (ushortT*)smem;              // 2 x 8192 shorts (32 KB)
        ushortT* SBb = (ushortT*)(smem + 32768);    // 2 x 7168 shorts (28 KB)
        ushortT* SMf = (ushortT*)(smem + 61440);    // 4096 shorts (8 KB)
        float*   rs  = (float*)(smem + 69632);      // 64 floats

        const int t = threadIdx.x, l = t & 63, w = t >> 6;
        const int g = l >> 4, c16 = l & 15;
        const int h = w >> 2;           // 0..1
        const int mtile = w & 3;        // 0..3
        const int m = mtile * 16 + c16; // owned bit-row
        const bool dg = ((mtile >> 1) == h);   // rowsum duty (waves 0,1,6,7)
        const short8v ONES = {0x3F80,0x3F80,0x3F80,0x3F80,
                              0x3F80,0x3F80,0x3F80,0x3F80};

        for (int i = t; i < 16384; i += 512) SAb[i] = 0;
        for (int i = t; i < 14336; i += 512) SBb[i] = 0;

        const float ci = 2.0f / 32768.0f;   // intra: mean over 64*512
        const float ce = 4.0f / 10000.0f;   // inter (VUL=1): 4/100^2
        const float cq = 2.0f / 6400.0f;    // quant (NTA=1)
        const float ce64 = 64.0f * ce;

        // ---- ownership: thread owns (m, n0..n0+3) per q; nt = 4h + q ----
        bool live[4];
        int sbO[4];
        float vreg[4][4], Kc[4][4], ncib[4][4];
        #pragma unroll
        for (int q = 0; q < 4; ++q) {
            const int nt = 4 * h + q;
            const int n0 = nt * 16 + 4 * g;
            const bool wact = (nt < 7);
            live[q] = wact && (n0 < NCLASS);
            // SB (transposed column) target: x = 16*(c16>>2) + (n&15)
            sbO[q] = ((nt * 2 + (mtile >> 1)) * 64 +
                      (16 * (c16 >> 2) + 4 * g + (c16 & 3))) * 8 + 4 * (mtile & 1);
            #pragma unroll
            for (int r = 0; r < 4; ++r) {
                float v = 0.f, bs = 0.f, cn = 0.f;
                if (live[q]) {
                    const int n = n0 + r;
                    v  = V[m * NCLASS + n];
                    bs = Bsum[m * NCLASS + n];
                    cn = count[n];
                }
                vreg[q][r] = v;
                Kc[q][r]   = ci * cn + cq - 128.f * ce;
                ncib[q][r] = -ci * bs;
            }
        }
        const int saO0 = (mtile * 4 + 2 * h) * 512 + l * 8;       // ks = 2h
        const int saO1 = saO0 + 512;                              // ks = 2h+1

        // store current vreg into buffers (SA pairs + SB quad-transpose)
        auto store_frags = [&](ushortT* SAn, ushortT* SBn) {
            uint4 wa;
            wa.x = cvtpk(vreg[0][0], vreg[0][1]);
            wa.y = cvtpk(vreg[0][2], vreg[0][3]);
            wa.z = cvtpk(vreg[1][0], vreg[1][1]);
            wa.w = cvtpk(vreg[1][2], vreg[1][3]);
            *(uint4*)&SAn[saO0] = wa;
            wa.x = cvtpk(vreg[2][0], vreg[2][1]);
            wa.y = cvtpk(vreg[2][2], vreg[2][3]);
            wa.z = cvtpk(vreg[3][0], vreg[3][1]);
            wa.w = cvtpk(vreg[3][2], vreg[3][3]);
            *(uint4*)&SAn[saO1] = wa;
            #pragma unroll
            for (int q = 0; q < 4; ++q) {
                if (4 * h + q < 7) {
                    float a0 = vreg[q][0], a1 = vreg[q][1];
                    float a2 = vreg[q][2], a3 = vreg[q][3];
                    // 4x4 transpose across the aligned quad (DPP, no LDS)
                    float t0 = dpp_x1(a1), t1 = dpp_x1(a0);
                    float t2 = dpp_x1(a3), t3 = dpp_x1(a2);
                    const bool o1 = (l & 1);
                    float c0 = o1 ? t0 : a0;
                    float c1 = o1 ? a1 : t1;
                    float c2 = o1 ? t2 : a2;
                    float c3 = o1 ? a3 : t3;
                    float u0 = dpp_x2(c2), u1 = dpp_x2(c3);
                    float u2 = dpp_x2(c0), u3 = dpp_x2(c1);
                    const bool o2 = (l & 2);
                    float d0 = o2 ? u0 : c0;
                    float d1 = o2 ? u1 : c1;
                    float d2 = o2 ? c2 : u2;
                    float d3 = o2 ? c3 : u3;
                    uint2 wb;
                    wb.x = cvtpk(d0, d1);
                    wb.y = cvtpk(d2, d3);
                    *(uint2*)&SBn[sbO[q]] = wb;
                }
            }
        };

        __syncthreads();          // zeros visible
        store_frags(SAb, SBb);    // fill buffer 0
        __syncthreads();

        int cur = 0;
        for (int step = 0; step < 200; ++step) {
            float alpha = 0.03f;
            if (step >= 149) alpha *= 0.1f;
            if (step >= 179) alpha *= 0.1f;

            const ushortT* SAc = SAb + cur * 8192;

            // ---- M = V V^T: vertical pair (2h, mtile), (2h+1, mtile) ----
            f32x4 aM0 = {0.f,0.f,0.f,0.f}, aM1 = {0.f,0.f,0.f,0.f};
            f32x4 aR  = {0.f,0.f,0.f,0.f};
            #pragma unroll
            for (int ks = 0; ks < 4; ++ks) {
                short8v b  = *(const short8v*)&SAc[mtile * 2048 + ks * 512 + l * 8];
                short8v a0 = *(const short8v*)&SAc[(2 * h) * 2048 + ks * 512 + l * 8];
                short8v a1 = *(const short8v*)&SAc[(2 * h + 1) * 2048 + ks * 512 + l * 8];
                aM0 = __builtin_amdgcn_mfma_f32_16x16x32_bf16(a0, b, aM0, 0, 0, 0);
                aM1 = __builtin_amdgcn_mfma_f32_16x16x32_bf16(a1, b, aM1, 0, 0, 0);
                if (dg)
                    aR = __builtin_amdgcn_mfma_f32_16x16x32_bf16(b, ONES, aR, 0, 0, 0);
            }
            {   // one conflict-free b128 into SM panel (mtile, h)
                uint4 sm;
                sm.x = cvtpk(aM0[0], aM0[1]);
                sm.y = cvtpk(aM0[2], aM0[3]);
                sm.z = cvtpk(aM1[0], aM1[1]);
                sm.w = cvtpk(aM1[2], aM1[3]);
                *(uint4*)&SMf[(mtile * 2 + h) * 512 + l * 8] = sm;
            }
            if (dg && c16 == 0)
                *(f32x4*)&rs[mtile * 16 + 4 * g] = aR;
            __syncthreads();

            // ---- P^T = V^T M : q-slots nt = 4h+q, shared B = SM[mtile] ----
            const ushortT* SBc = SBb + cur * 7168;
            f32x4 p[4];
            #pragma unroll
            for (int q = 0; q < 4; ++q) p[q] = (f32x4){0.f,0.f,0.f,0.f};
            #pragma unroll
            for (int kb = 0; kb < 2; ++kb) {
                short8v bP = *(const short8v*)&SMf[(mtile * 2 + kb) * 512 + l * 8];
                #pragma unroll
                for (int q = 0; q < 4; ++q) {
                    if (4 * h + q < 7) {
                        short8v aP = *(const short8v*)
                            &SBc[((4 * h + q) * 2 + kb) * 512 + l * 8];
                        p[q] = __builtin_amdgcn_mfma_f32_16x16x32_bf16(aP, bP, p[q], 0, 0, 0);
                    }
                }
            }
            const float rsm = rs[m];

            // ---- update own elements, store into NEXT buffers ----
            #pragma unroll
            for (int q = 0; q < 4; ++q) {
                if (4 * h + q < 7) {
                    #pragma unroll
                    for (int r = 0; r < 4; ++r) {
                        const float v = vreg[q][r];
                        float t1 = __builtin_fmaf(Kc[q][r], v, ncib[q][r]);
                        t1 = __builtin_fmaf(ce,   p[q][r], t1);
                        t1 = __builtin_fmaf(ce64, rsm,     t1);
                        t1 -= __builtin_copysignf(cq, v);
                        float vn = __builtin_fmaf(-alpha, t1, v);
                        vreg[q][r] = live[q] ? vn : 0.f;
                    }
                }
            }
            store_frags(SAb + (cur ^ 1) * 8192, SBb + (cur ^ 1) * 7168);
            __syncthreads();
            cur ^= 1;
        }

        // write V_new from f32 register master copy
        #pragma unroll
        for (int q = 0; q < 4; ++q) {
            if (live[q]) {
                const int n0 = (4 * h + q) * 16 + 4 * g;
                #pragma unroll
                for (int r = 0; r < 4; ++r)
                    out[1 + m * NCLASS + n0 + r] = vreg[q][r];
            }
        }
    } else {
        // ================= metric =================
        float*  ut   = (float*)smem;                // [2][64*68]
        int*    slab = (int*)(smem + 34816);        // [512]
        double* wsum = (double*)(smem + 36864);     // [8]
        int*    tls  = (int*)(smem + 36928);        // [256]

        const int t = threadIdx.x;
        const int jj = t & 255;
        const int j = (blockIdx.x - 1) * 256 + jj;
        const int half = t >> 8;
        const bool jok = (j < NTRAIN);
        slab[t] = lab[t];

        // local tlab slice from one-hot Y, patched by the scatter
        if (half == 0) {
            int tl = 0;
            if (jok) {
                for (int c = 0; c < NCLASS; ++c)
                    if (Y[(size_t)c * NTRAIN + j] > 0.5f) tl = c;
                int ow = owner[j];
                if (ow >= 0) tl = lab[ow];
            }
            tls[jj] = tl;
        }
        __syncthreads();
        const int tl = tls[jj];

        const float* colbase = U;
        size_t cstride = NTRAIN;
        if (jok) {
            int ow = owner[j];
            if (ow >= 0) { colbase = u + (size_t)ow * BIT; cstride = 1; }
            else         { colbase = U + j; }
        }

        float lsum = 0.f;
        for (int ch = 0; ch < 4; ++ch) {
            __syncthreads();   // previous chunk's readers done
            for (int i = t; i < 8192; i += 512) {
                int buf = i >> 12, k = (i >> 6) & 63, r = i & 63;
                ut[buf * 4352 + r * 68 + k] = u[((buf * 4 + ch) * 64 + k) * BIT + r];
            }
            __syncthreads();

            if (jok) {
                const float* myut = ut + half * 4352;
                float acc[64];
                #pragma unroll
                for (int k = 0; k < 64; ++k) acc[k] = 0.f;
                #pragma unroll 2
                for (int r = 0; r < BIT; ++r) {
                    float Uv = colbase[(size_t)r * cstride];
                    const float* urow = &myut[r * 68];
                    #pragma unroll
                    for (int qq = 0; qq < 16; ++qq) {
                        float4 uv = *(const float4*)&urow[qq * 4];
                        acc[4 * qq + 0] += uv.x * Uv;
                        acc[4 * qq + 1] += uv.y * Uv;
                        acc[4 * qq + 2] += uv.z * Uv;
                        acc[4 * qq + 3] += uv.w * Uv;
                    }
                }
                const int b0 = (half * 4 + ch) * 64;
                #pragma unroll
                for (int k = 0; k < 64; ++k) {
                    float ip = fminf(fmaxf(0.5f * acc[k], -100.f), 50.f);
                    float x = (slab[b0 + k] == tl) ? (1.0f - ip) : (1.0f + ip); // M=1
                    lsum += fmaxf(x, 0.f) + __logf(1.f + __expf(-fabsf(x)));
                }
            }
        }

        double d = (double)lsum;
        for (int off = 32; off; off >>= 1) d += __shfl_down(d, off);
        const int wid = t >> 6, lane = t & 63;
        if (lane == 0) wsum[wid] = d;
        __syncthreads();
        if (t == 0) {
            double s = 0;
            for (int ww = 0; ww < 8; ++ww) s += wsum[ww];
            atomicAdd(msum, s);
        }
    }
}

__global__ void k_final(const double* __restrict__ msum,
                        const double* __restrict__ qsum, float* out) {
    if (threadIdx.x == 0) {
        double loss = (*msum) / ((double)BATCH * (double)NTRAIN)
                    + 0.5 * ((*qsum) / ((double)BIT * (double)BATCH));
        out[0] = (float)loss;
    }
}

extern "C" void kernel_launch(void* const* d_in, const int* in_sizes, int n_in,
                              void* d_out, int out_size, void* d_ws, size_t ws_size,
                              hipStream_t stream) {
    const float* u   = (const float*)d_in[0];
    const float* y   = (const float*)d_in[1];
    const int*   ind = (const int*)d_in[2];
    const float* U   = (const float*)d_in[3];
    const float* Y   = (const float*)d_in[4];
    const float* V   = (const float*)d_in[5];
    float* out = (float*)d_out;

    int*   wsI = (int*)d_ws;
    float* wsF = (float*)d_ws;
    int*   owner = wsI + O_OWNER;
    int*   lab   = wsI + O_LAB;
    float* bmat  = wsF + O_BMAT;
    float* Bsum  = wsF + O_BSUM;
    float* count = wsF + O_COUNT;
    double* qsum = (double*)(wsF + O_QSUM);
    double* msum = (double*)(wsF + O_MSUM);

    hipMemsetAsync(owner, 0xFF, NTRAIN * sizeof(int), stream);        // -1
    hipMemsetAsync(wsF + O_QSUM, 0, 4 * sizeof(float), stream);       // qsum,msum

    k_prep<<<1, 512, 0, stream>>>(y, ind, owner, lab);
    k_b<<<64, 512, 0, stream>>>(u, V, lab, bmat, qsum);
    k_bsum<<<25, 256, 0, stream>>>(bmat, lab, Bsum, count);
    k_main<<<1 + (NTRAIN + 255) / 256, 512, 0, stream>>>(
        V, Bsum, count, u, U, Y, lab, owner, msum, out);
    k_final<<<1, 64, 0, stream>>>(msum, qsum, out);
}